// Round 1
// baseline (1749.925 us; speedup 1.0000x reference)
//
#include <hip/hip_runtime.h>
#include <math.h>

// ---------------------------------------------------------------------------
// Round 0: correctness-first fp32 implementation.
//   kernel 1/3: gemm_nt  C[m,n] = sum_k A[m,k] * Bt[n,k]   (A row-major, Bt row-major over k)
//   kernel 2:   flash-style causal attention, 64-row Q tiles, online softmax
// Workspace layout (d_ws): qkv [M,3072] fp32 (96 MiB) | attn_out [M,1024] fp32 (32 MiB)
// ---------------------------------------------------------------------------

#define TILE_BM 128
#define TILE_BN 128
#define TILE_BK 16

__global__ __launch_bounds__(256)
void gemm_nt(const float* __restrict__ A, const float* __restrict__ Bt,
             float* __restrict__ C, int M, int N, int K)
{
    __shared__ float As[TILE_BK][TILE_BM + 4];   // [k][m], +4 pad keeps rows 16B-aligned, no conflicts
    __shared__ float Bs[TILE_BK][TILE_BN + 4];
    const int tid = threadIdx.x;
    const int tx = tid & 15;    // 0..15 -> 8-col group
    const int ty = tid >> 4;    // 0..15 -> 8-row group
    const int m0 = blockIdx.y * TILE_BM;
    const int n0 = blockIdx.x * TILE_BN;

    float acc[8][8];
#pragma unroll
    for (int i = 0; i < 8; ++i)
#pragma unroll
        for (int j = 0; j < 8; ++j) acc[i][j] = 0.f;

    for (int k0 = 0; k0 < K; k0 += TILE_BK) {
        // stage 128x16 tiles of A and Bt: 512 float4 each, 2 per thread
#pragma unroll
        for (int t = 0; t < 2; ++t) {
            int idx = tid + t * 256;
            int r   = idx >> 2;          // 0..127
            int kq  = (idx & 3) * 4;     // 0,4,8,12
            float4 a = *(const float4*)(A + (size_t)(m0 + r) * K + k0 + kq);
            As[kq+0][r] = a.x; As[kq+1][r] = a.y; As[kq+2][r] = a.z; As[kq+3][r] = a.w;
            float4 b = *(const float4*)(Bt + (size_t)(n0 + r) * K + k0 + kq);
            Bs[kq+0][r] = b.x; Bs[kq+1][r] = b.y; Bs[kq+2][r] = b.z; Bs[kq+3][r] = b.w;
        }
        __syncthreads();
#pragma unroll
        for (int k = 0; k < TILE_BK; ++k) {
            float ar[8], br[8];
            *(float4*)&ar[0] = *(const float4*)&As[k][ty*8];
            *(float4*)&ar[4] = *(const float4*)&As[k][ty*8+4];
            *(float4*)&br[0] = *(const float4*)&Bs[k][tx*8];
            *(float4*)&br[4] = *(const float4*)&Bs[k][tx*8+4];
#pragma unroll
            for (int i = 0; i < 8; ++i)
#pragma unroll
                for (int j = 0; j < 8; ++j)
                    acc[i][j] = fmaf(ar[i], br[j], acc[i][j]);
        }
        __syncthreads();
    }
#pragma unroll
    for (int i = 0; i < 8; ++i) {
        float* crow = C + (size_t)(m0 + ty*8 + i) * N + n0 + tx*8;
        *(float4*)(crow)     = make_float4(acc[i][0], acc[i][1], acc[i][2], acc[i][3]);
        *(float4*)(crow + 4) = make_float4(acc[i][4], acc[i][5], acc[i][6], acc[i][7]);
    }
}

// ---------------------------------------------------------------------------
// Flash-style causal attention.
// grid: (T/64, H, B), 256 threads. Thread (ty,tx) owns a 4x4 patch:
//   rows q0+4ty..+3, score-cols k0+4tx..+3, out-cols (d) 4tx..+3.
// Row-group = 16 consecutive lanes of one wave -> __shfl_xor width 16 reductions.
// LDS: Qs (q-major), KVs (K-phase: [d][krow] transposed; V-phase: [krow][d]), Ps.
// 3 x 64x68 x 4B = 52 KB static.
// ---------------------------------------------------------------------------
__global__ __launch_bounds__(256)
void attn_fwd(const float* __restrict__ qkv, float* __restrict__ out, int T)
{
    __shared__ float Qs[64][68];
    __shared__ float KVs[64][68];
    __shared__ float Ps[64][68];
    const int tid = threadIdx.x;
    const int tx = tid & 15;
    const int ty = tid >> 4;
    const int qt = blockIdx.x;
    const int h  = blockIdx.y;
    const int b  = blockIdx.z;
    const int q0 = qt * 64;
    const size_t C3 = 3072;
    const float* base = qkv + (size_t)b * T * C3;
    const float* qb = base + h * 64;
    const float* kb = base + 1024 + h * 64;
    const float* vb = base + 2048 + h * 64;

    // stage Q tile, pre-scaled by Dh^-0.5 = 1/8
#pragma unroll
    for (int t = 0; t < 4; ++t) {
        int idx = tid + 256 * t;
        int r = idx >> 4;
        int c = (idx & 15) * 4;
        float4 q = *(const float4*)(qb + (size_t)(q0 + r) * C3 + c);
        q.x *= 0.125f; q.y *= 0.125f; q.z *= 0.125f; q.w *= 0.125f;
        *(float4*)&Qs[r][c] = q;
    }

    float m_i[4], l_i[4], o[4][4];
#pragma unroll
    for (int i = 0; i < 4; ++i) {
        m_i[i] = -__builtin_inff();
        l_i[i] = 0.f;
#pragma unroll
        for (int j = 0; j < 4; ++j) o[i][j] = 0.f;
    }

    for (int kt = 0; kt <= qt; ++kt) {
        const int k0 = kt * 64;
        // prefetch V tile into registers (overlaps with S compute)
        float4 vreg[4];
#pragma unroll
        for (int t = 0; t < 4; ++t) {
            int idx = tid + 256 * t;
            int vr = idx >> 4;
            int vc = (idx & 15) * 4;
            vreg[t] = *(const float4*)(vb + (size_t)(k0 + vr) * C3 + vc);
        }
        // stage K transposed: KVs[d][krow]. Lane-major over krow -> conflict-free scatter.
        {
            int kr = tid & 63;
            int cq = tid >> 6;   // wave id: column quads
#pragma unroll
            for (int t = 0; t < 4; ++t) {
                int c4 = cq * 4 + t;
                float4 kv = *(const float4*)(kb + (size_t)(k0 + kr) * C3 + c4 * 4);
                KVs[c4*4+0][kr] = kv.x;
                KVs[c4*4+1][kr] = kv.y;
                KVs[c4*4+2][kr] = kv.z;
                KVs[c4*4+3][kr] = kv.w;
            }
        }
        __syncthreads();  // K (and Q on first iter) visible

        // S = (Q/8) K^T
        float s[4][4];
#pragma unroll
        for (int i = 0; i < 4; ++i)
#pragma unroll
            for (int j = 0; j < 4; ++j) s[i][j] = 0.f;
#pragma unroll 8
        for (int d = 0; d < 64; ++d) {
            float qa[4];
#pragma unroll
            for (int i = 0; i < 4; ++i) qa[i] = Qs[ty*4+i][d];   // 16-lane broadcast
            float4 kv4 = *(const float4*)&KVs[d][tx*4];
#pragma unroll
            for (int i = 0; i < 4; ++i) {
                s[i][0] = fmaf(qa[i], kv4.x, s[i][0]);
                s[i][1] = fmaf(qa[i], kv4.y, s[i][1]);
                s[i][2] = fmaf(qa[i], kv4.z, s[i][2]);
                s[i][3] = fmaf(qa[i], kv4.w, s[i][3]);
            }
        }
        // causal mask: only the diagonal tile can have k > q
        if (kt == qt) {
#pragma unroll
            for (int i = 0; i < 4; ++i)
#pragma unroll
                for (int j = 0; j < 4; ++j)
                    if (k0 + tx*4 + j > q0 + ty*4 + i) s[i][j] = -__builtin_inff();
        }
        // online softmax per owned row
#pragma unroll
        for (int i = 0; i < 4; ++i) {
            float mx = fmaxf(fmaxf(s[i][0], s[i][1]), fmaxf(s[i][2], s[i][3]));
#pragma unroll
            for (int off = 1; off < 16; off <<= 1)
                mx = fmaxf(mx, __shfl_xor(mx, off, 16));
            float m_new = fmaxf(m_i[i], mx);
            float alpha = __expf(m_i[i] - m_new);   // first tile: exp(-inf)=0
            float p0 = __expf(s[i][0] - m_new);
            float p1 = __expf(s[i][1] - m_new);
            float p2 = __expf(s[i][2] - m_new);
            float p3 = __expf(s[i][3] - m_new);
            float rs = (p0 + p1) + (p2 + p3);
#pragma unroll
            for (int off = 1; off < 16; off <<= 1)
                rs += __shfl_xor(rs, off, 16);
            l_i[i] = l_i[i] * alpha + rs;
            m_i[i] = m_new;
            o[i][0] *= alpha; o[i][1] *= alpha; o[i][2] *= alpha; o[i][3] *= alpha;
            *(float4*)&Ps[ty*4+i][tx*4] = make_float4(p0, p1, p2, p3);
        }
        __syncthreads();  // Ps visible; S-phase KVs reads complete
        // stage V (row-major) into KVs from registers
#pragma unroll
        for (int t = 0; t < 4; ++t) {
            int idx = tid + 256 * t;
            int vr = idx >> 4;
            int vc = (idx & 15) * 4;
            *(float4*)&KVs[vr][vc] = vreg[t];
        }
        __syncthreads();  // V visible
        // O += P V
#pragma unroll 8
        for (int kk = 0; kk < 64; ++kk) {
            float pa[4];
#pragma unroll
            for (int i = 0; i < 4; ++i) pa[i] = Ps[ty*4+i][kk];  // broadcast
            float4 vv = *(const float4*)&KVs[kk][tx*4];
#pragma unroll
            for (int i = 0; i < 4; ++i) {
                o[i][0] = fmaf(pa[i], vv.x, o[i][0]);
                o[i][1] = fmaf(pa[i], vv.y, o[i][1]);
                o[i][2] = fmaf(pa[i], vv.z, o[i][2]);
                o[i][3] = fmaf(pa[i], vv.w, o[i][3]);
            }
        }
        __syncthreads();  // PV done before next-iter staging overwrites KVs/Ps
    }

    // epilogue: normalize and write [B,T,C] with heads re-interleaved
    const size_t C = 1024;
    float* ob = out + (size_t)b * T * C + h * 64;
#pragma unroll
    for (int i = 0; i < 4; ++i) {
        float inv = 1.f / l_i[i];
        float4 r = make_float4(o[i][0]*inv, o[i][1]*inv, o[i][2]*inv, o[i][3]*inv);
        *(float4*)(ob + (size_t)(q0 + ty*4 + i) * C + tx*4) = r;
    }
}

extern "C" void kernel_launch(void* const* d_in, const int* in_sizes, int n_in,
                              void* d_out, int out_size, void* d_ws, size_t ws_size,
                              hipStream_t stream)
{
    const float* x     = (const float*)d_in[0];
    const float* W_qkv = (const float*)d_in[1];
    const float* W_out = (const float*)d_in[2];
    float* out = (float*)d_out;

    const int C = 1024;
    const int T = 2048;
    const int M = in_sizes[0] / C;   // B*T = 8192
    const int B = M / T;             // 4

    float* qkv      = (float*)d_ws;                  // M x 3C
    float* attn_out = qkv + (size_t)M * 3 * C;       // M x C   (ws total: 128 MiB)

    // qkv[m][o] = sum_c x[m][c] * W_qkv[o][c]
    gemm_nt<<<dim3((3*C)/TILE_BN, M/TILE_BM), 256, 0, stream>>>(x, W_qkv, qkv, M, 3*C, C);
    // causal flash attention per (b,h,q-tile)
    attn_fwd<<<dim3(T/64, 16, B), 256, 0, stream>>>(qkv, attn_out, T);
    // out[m][o] = sum_c attn_out[m][c] * W_out[o][c]
    gemm_nt<<<dim3(C/TILE_BN, M/TILE_BM), 256, 0, stream>>>(attn_out, W_out, out, M, C, C);
}

// Round 2
// 989.673 us; speedup vs baseline: 1.7682x; 1.7682x over previous
//
#include <hip/hip_runtime.h>
#include <hip/hip_bf16.h>
#include <math.h>

// ---------------------------------------------------------------------------
// Round 1: bf16-MFMA projections (m97 ladder structure), fp32 flash attention
//   cast kernels: x, W_qkv, W_out fp32->bf16
//   gemm_bf16_nt: C[m,n] = sum_k A[m,k]*Bt[n,k], 128x128 tile, 16x16x32 MFMA,
//                 global_load_lds width-16 staging, 2-barrier K-loop
//   attn_fwd: flash causal attention, bf16 in/out, fp32 math (MFMA next round)
// Workspace (88 MiB): x_bf 16 | Wqkv_bf 6 | Wout_bf 2 | qkv_bf 48 | ao_bf 16
// ---------------------------------------------------------------------------

typedef __attribute__((ext_vector_type(8))) short bf16x8;
typedef __attribute__((ext_vector_type(4))) float f32x4;

__device__ __forceinline__ float b2f(unsigned short u) {
    unsigned int v = ((unsigned int)u) << 16;
    return __uint_as_float(v);
}

__device__ __forceinline__ void async16(const void* g, void* l) {
    __builtin_amdgcn_global_load_lds((const __attribute__((address_space(1))) void*)g,
                                     (__attribute__((address_space(3))) void*)l,
                                     16, 0, 0);
}

// ---------------------------------------------------------------------------
__global__ __launch_bounds__(256)
void cast_f32_bf16(const float* __restrict__ in, unsigned short* __restrict__ out, int n)
{
    int i = (blockIdx.x * 256 + threadIdx.x) * 8;
    if (i + 8 > n) return;
    float4 a = *(const float4*)(in + i);
    float4 b = *(const float4*)(in + i + 4);
    __hip_bfloat16 r[8];
    r[0] = __float2bfloat16(a.x); r[1] = __float2bfloat16(a.y);
    r[2] = __float2bfloat16(a.z); r[3] = __float2bfloat16(a.w);
    r[4] = __float2bfloat16(b.x); r[5] = __float2bfloat16(b.y);
    r[6] = __float2bfloat16(b.z); r[7] = __float2bfloat16(b.w);
    *(float4*)(out + i) = *(float4*)r;
}

// ---------------------------------------------------------------------------
// bf16 NT GEMM: A [M,K] row-major, Bt [N,K] row-major, both bf16.
// Block 256 thr = 4 waves in 2x2; wave tile 64x64 = 4x4 MFMA 16x16x32 tiles.
// LDS: As/Bs 128x32 bf16 row-major (64 B/row) -- matches global_load_lds
// lane-order (wave base + lane*16), no padding allowed.
// ---------------------------------------------------------------------------
template <typename OutT>
__global__ __launch_bounds__(256)
void gemm_bf16_nt(const unsigned short* __restrict__ A,
                  const unsigned short* __restrict__ Bt,
                  OutT* __restrict__ C, int M, int N, int K)
{
    __shared__ unsigned short As[128 * 32];
    __shared__ unsigned short Bs[128 * 32];
    const int tid  = threadIdx.x;
    const int lane = tid & 63;
    const int wave = tid >> 6;
    const int wm   = wave >> 1;   // 0..1
    const int wn   = wave & 1;    // 0..1
    const int m0   = blockIdx.y * 128;
    const int n0   = blockIdx.x * 128;

    f32x4 acc[4][4];
#pragma unroll
    for (int i = 0; i < 4; ++i)
#pragma unroll
        for (int j = 0; j < 4; ++j) acc[i][j] = (f32x4){0.f, 0.f, 0.f, 0.f};

    // staging addresses: call c (c=0,1): LDS byte off = c*4096 + tid*16
    //   -> row = c*64 + (tid>>2), col elems = (tid&3)*8
    const int srow = tid >> 2;
    const int scol = (tid & 3) * 8;
    const int wbase = wave * 512;           // ushort offset of wave's 1 KB chunk

    // fragment read indices (per wave)
    const int fr = lane & 15;               // row within 16-tile
    const int fk = (lane >> 4) * 8;         // k offset 0/8/16/24

    for (int k0 = 0; k0 < K; k0 += 32) {
#pragma unroll
        for (int c = 0; c < 2; ++c) {
            const unsigned short* ga = A + (size_t)(m0 + c * 64 + srow) * K + k0 + scol;
            async16(ga, As + c * 2048 + wbase);
            const unsigned short* gb = Bt + (size_t)(n0 + c * 64 + srow) * K + k0 + scol;
            async16(gb, Bs + c * 2048 + wbase);
        }
        __syncthreads();   // compiler drains vmcnt before s_barrier

        bf16x8 af[4], bf[4];
#pragma unroll
        for (int mi = 0; mi < 4; ++mi)
            af[mi] = *(const bf16x8*)&As[(wm * 64 + mi * 16 + fr) * 32 + fk];
#pragma unroll
        for (int ni = 0; ni < 4; ++ni)
            bf[ni] = *(const bf16x8*)&Bs[(wn * 64 + ni * 16 + fr) * 32 + fk];
#pragma unroll
        for (int mi = 0; mi < 4; ++mi)
#pragma unroll
            for (int ni = 0; ni < 4; ++ni)
                acc[mi][ni] = __builtin_amdgcn_mfma_f32_16x16x32_bf16(
                    af[mi], bf[ni], acc[mi][ni], 0, 0, 0);
        __syncthreads();   // all waves done reading before next stage overwrites
    }

    // epilogue: C/D map col = lane&15, row = (lane>>4)*4 + r
    const int ccol  = n0 + wn * 64 + (lane & 15);
    const int crow0 = m0 + wm * 64 + (lane >> 4) * 4;
#pragma unroll
    for (int mi = 0; mi < 4; ++mi) {
#pragma unroll
        for (int r = 0; r < 4; ++r) {
            const size_t row = (size_t)(crow0 + mi * 16 + r);
#pragma unroll
            for (int ni = 0; ni < 4; ++ni) {
                float v = acc[mi][ni][r];
                if constexpr (__is_same(OutT, float)) {
                    C[row * N + ccol + ni * 16] = v;
                } else {
                    __hip_bfloat16 h = __float2bfloat16(v);
                    C[row * N + ccol + ni * 16] = *(unsigned short*)&h;
                }
            }
        }
    }
}

// ---------------------------------------------------------------------------
// Flash-style causal attention, bf16 qkv in, bf16 out, fp32 math.
// grid: (T/64, H, B), 256 threads. Thread (ty,tx) owns 4x4 patch.
// LDS: Qs, KVs (K-phase transposed [d][krow]; V-phase [krow][d]), Ps. 52 KB.
// ---------------------------------------------------------------------------
__global__ __launch_bounds__(256)
void attn_fwd(const unsigned short* __restrict__ qkv, unsigned short* __restrict__ out, int T)
{
    __shared__ float Qs[64][68];
    __shared__ float KVs[64][68];
    __shared__ float Ps[64][68];
    const int tid = threadIdx.x;
    const int tx = tid & 15;
    const int ty = tid >> 4;
    const int qt = blockIdx.x;
    const int h  = blockIdx.y;
    const int b  = blockIdx.z;
    const int q0 = qt * 64;
    const size_t C3 = 3072;
    const unsigned short* base = qkv + (size_t)b * T * C3;
    const unsigned short* qb = base + h * 64;
    const unsigned short* kb = base + 1024 + h * 64;
    const unsigned short* vb = base + 2048 + h * 64;

    // stage Q tile (bf16 -> fp32), pre-scaled by Dh^-0.5 = 1/8
#pragma unroll
    for (int t = 0; t < 2; ++t) {
        int idx = tid + 256 * t;
        int r = idx >> 3;
        int c = (idx & 7) * 8;
        float4 raw = *(const float4*)(qb + (size_t)(q0 + r) * C3 + c);
        const unsigned short* u = (const unsigned short*)&raw;
#pragma unroll
        for (int j = 0; j < 8; ++j) Qs[r][c + j] = b2f(u[j]) * 0.125f;
    }

    float m_i[4], l_i[4], o[4][4];
#pragma unroll
    for (int i = 0; i < 4; ++i) {
        m_i[i] = -__builtin_inff();
        l_i[i] = 0.f;
#pragma unroll
        for (int j = 0; j < 4; ++j) o[i][j] = 0.f;
    }

    for (int kt = 0; kt <= qt; ++kt) {
        const int k0 = kt * 64;
        // prefetch V tile into registers (16 bf16/thread)
        float4 vraw[2];
#pragma unroll
        for (int t = 0; t < 2; ++t) {
            int idx = tid + 256 * t;
            int vr = idx >> 3;
            int vc = (idx & 7) * 8;
            vraw[t] = *(const float4*)(vb + (size_t)(k0 + vr) * C3 + vc);
        }
        // stage K transposed: KVs[d][krow]
        {
            int kr = tid & 63;
            int cq = tid >> 6;
#pragma unroll
            for (int t = 0; t < 2; ++t) {
                int c8 = cq * 16 + t * 8;
                float4 raw = *(const float4*)(kb + (size_t)(k0 + kr) * C3 + c8);
                const unsigned short* u = (const unsigned short*)&raw;
#pragma unroll
                for (int j = 0; j < 8; ++j) KVs[c8 + j][kr] = b2f(u[j]);
            }
        }
        __syncthreads();

        // S = (Q/8) K^T
        float s[4][4];
#pragma unroll
        for (int i = 0; i < 4; ++i)
#pragma unroll
            for (int j = 0; j < 4; ++j) s[i][j] = 0.f;
#pragma unroll 8
        for (int d = 0; d < 64; ++d) {
            float qa[4];
#pragma unroll
            for (int i = 0; i < 4; ++i) qa[i] = Qs[ty*4+i][d];
            float4 kv4 = *(const float4*)&KVs[d][tx*4];
#pragma unroll
            for (int i = 0; i < 4; ++i) {
                s[i][0] = fmaf(qa[i], kv4.x, s[i][0]);
                s[i][1] = fmaf(qa[i], kv4.y, s[i][1]);
                s[i][2] = fmaf(qa[i], kv4.z, s[i][2]);
                s[i][3] = fmaf(qa[i], kv4.w, s[i][3]);
            }
        }
        if (kt == qt) {
#pragma unroll
            for (int i = 0; i < 4; ++i)
#pragma unroll
                for (int j = 0; j < 4; ++j)
                    if (k0 + tx*4 + j > q0 + ty*4 + i) s[i][j] = -__builtin_inff();
        }
#pragma unroll
        for (int i = 0; i < 4; ++i) {
            float mx = fmaxf(fmaxf(s[i][0], s[i][1]), fmaxf(s[i][2], s[i][3]));
#pragma unroll
            for (int off = 1; off < 16; off <<= 1)
                mx = fmaxf(mx, __shfl_xor(mx, off, 16));
            float m_new = fmaxf(m_i[i], mx);
            float alpha = __expf(m_i[i] - m_new);
            float p0 = __expf(s[i][0] - m_new);
            float p1 = __expf(s[i][1] - m_new);
            float p2 = __expf(s[i][2] - m_new);
            float p3 = __expf(s[i][3] - m_new);
            float rs = (p0 + p1) + (p2 + p3);
#pragma unroll
            for (int off = 1; off < 16; off <<= 1)
                rs += __shfl_xor(rs, off, 16);
            l_i[i] = l_i[i] * alpha + rs;
            m_i[i] = m_new;
            o[i][0] *= alpha; o[i][1] *= alpha; o[i][2] *= alpha; o[i][3] *= alpha;
            *(float4*)&Ps[ty*4+i][tx*4] = make_float4(p0, p1, p2, p3);
        }
        __syncthreads();
        // stage V (row-major, bf16->fp32) from registers
#pragma unroll
        for (int t = 0; t < 2; ++t) {
            int idx = tid + 256 * t;
            int vr = idx >> 3;
            int vc = (idx & 7) * 8;
            const unsigned short* u = (const unsigned short*)&vraw[t];
#pragma unroll
            for (int j = 0; j < 8; ++j) KVs[vr][vc + j] = b2f(u[j]);
        }
        __syncthreads();
        // O += P V
#pragma unroll 8
        for (int kk = 0; kk < 64; ++kk) {
            float pa[4];
#pragma unroll
            for (int i = 0; i < 4; ++i) pa[i] = Ps[ty*4+i][kk];
            float4 vv = *(const float4*)&KVs[kk][tx*4];
#pragma unroll
            for (int i = 0; i < 4; ++i) {
                o[i][0] = fmaf(pa[i], vv.x, o[i][0]);
                o[i][1] = fmaf(pa[i], vv.y, o[i][1]);
                o[i][2] = fmaf(pa[i], vv.z, o[i][2]);
                o[i][3] = fmaf(pa[i], vv.w, o[i][3]);
            }
        }
        __syncthreads();
    }

    // epilogue: normalize, convert to bf16, write [B,T,C] head-interleaved
    const size_t C = 1024;
    unsigned short* ob = out + (size_t)b * T * C + h * 64;
#pragma unroll
    for (int i = 0; i < 4; ++i) {
        float inv = 1.f / l_i[i];
        __hip_bfloat16 r4[4];
        r4[0] = __float2bfloat16(o[i][0] * inv);
        r4[1] = __float2bfloat16(o[i][1] * inv);
        r4[2] = __float2bfloat16(o[i][2] * inv);
        r4[3] = __float2bfloat16(o[i][3] * inv);
        *(float2*)(ob + (size_t)(q0 + ty*4 + i) * C + tx*4) = *(float2*)r4;
    }
}

// ---------------------------------------------------------------------------
extern "C" void kernel_launch(void* const* d_in, const int* in_sizes, int n_in,
                              void* d_out, int out_size, void* d_ws, size_t ws_size,
                              hipStream_t stream)
{
    const float* x     = (const float*)d_in[0];
    const float* W_qkv = (const float*)d_in[1];
    const float* W_out = (const float*)d_in[2];
    float* out = (float*)d_out;

    const int C = 1024;
    const int T = 2048;
    const int M = in_sizes[0] / C;   // 8192
    const int B = M / T;             // 4
    const int n_x    = in_sizes[0];  // 8388608
    const int n_wqkv = in_sizes[1];  // 3145728
    const int n_wout = in_sizes[2];  // 1048576

    unsigned short* x_bf    = (unsigned short*)d_ws;
    unsigned short* wqkv_bf = x_bf    + n_x;
    unsigned short* wout_bf = wqkv_bf + n_wqkv;
    unsigned short* qkv_bf  = wout_bf + n_wout;            // M x 3C
    unsigned short* ao_bf   = qkv_bf  + (size_t)M * 3 * C; // M x C

    cast_f32_bf16<<<n_x    / 2048, 256, 0, stream>>>(x,     x_bf,    n_x);
    cast_f32_bf16<<<n_wqkv / 2048, 256, 0, stream>>>(W_qkv, wqkv_bf, n_wqkv);
    cast_f32_bf16<<<n_wout / 2048, 256, 0, stream>>>(W_out, wout_bf, n_wout);

    gemm_bf16_nt<unsigned short><<<dim3((3*C)/128, M/128), 256, 0, stream>>>(
        x_bf, wqkv_bf, qkv_bf, M, 3*C, C);

    attn_fwd<<<dim3(T/64, 16, B), 256, 0, stream>>>(qkv_bf, ao_bf, T);

    gemm_bf16_nt<float><<<dim3(C/128, M/128), 256, 0, stream>>>(
        ao_bf, wout_bf, out, M, C, C);
}

// Round 3
// 423.145 us; speedup vs baseline: 4.1355x; 2.3389x over previous
//
#include <hip/hip_runtime.h>
#include <hip/hip_bf16.h>
#include <math.h>

// ---------------------------------------------------------------------------
// Round 2: MFMA everywhere.
//   casts: x, W_qkv, W_out fp32->bf16
//   gemm_bf16_nt: m97-style 128x128 bf16 MFMA GEMM (unchanged from round 1)
//   transpose_v: V slice of qkv -> Vt [B,H,64,T] bf16 (LDS-tiled)
//   attn_mfma: flash causal attention, 16x16x32 bf16 MFMA for QK^T and PV,
//              online softmax in C/D layout, P routed through LDS (C/D->A).
// Workspace (~104 MiB): x_bf | Wqkv_bf | Wout_bf | qkv_bf | vt_bf | ao_bf
// ---------------------------------------------------------------------------

typedef __attribute__((ext_vector_type(8))) short bf16x8;
typedef __attribute__((ext_vector_type(4))) float f32x4;

__device__ __forceinline__ void async16(const void* g, void* l) {
    __builtin_amdgcn_global_load_lds((const __attribute__((address_space(1))) void*)g,
                                     (__attribute__((address_space(3))) void*)l,
                                     16, 0, 0);
}

__device__ __forceinline__ unsigned short f2b(float f) {
    __hip_bfloat16 h = __float2bfloat16(f);
    return *(unsigned short*)&h;
}

// ---------------------------------------------------------------------------
__global__ __launch_bounds__(256)
void cast_f32_bf16(const float* __restrict__ in, unsigned short* __restrict__ out, int n)
{
    int i = (blockIdx.x * 256 + threadIdx.x) * 8;
    if (i + 8 > n) return;
    float4 a = *(const float4*)(in + i);
    float4 b = *(const float4*)(in + i + 4);
    __hip_bfloat16 r[8];
    r[0] = __float2bfloat16(a.x); r[1] = __float2bfloat16(a.y);
    r[2] = __float2bfloat16(a.z); r[3] = __float2bfloat16(a.w);
    r[4] = __float2bfloat16(b.x); r[5] = __float2bfloat16(b.y);
    r[6] = __float2bfloat16(b.z); r[7] = __float2bfloat16(b.w);
    *(float4*)(out + i) = *(float4*)r;
}

// ---------------------------------------------------------------------------
// bf16 NT GEMM (round-1 verified): A [M,K], Bt [N,K] row-major bf16.
// ---------------------------------------------------------------------------
template <typename OutT>
__global__ __launch_bounds__(256)
void gemm_bf16_nt(const unsigned short* __restrict__ A,
                  const unsigned short* __restrict__ Bt,
                  OutT* __restrict__ C, int M, int N, int K)
{
    __shared__ unsigned short As[128 * 32];
    __shared__ unsigned short Bs[128 * 32];
    const int tid  = threadIdx.x;
    const int lane = tid & 63;
    const int wave = tid >> 6;
    const int wm   = wave >> 1;
    const int wn   = wave & 1;
    const int m0   = blockIdx.y * 128;
    const int n0   = blockIdx.x * 128;

    f32x4 acc[4][4];
#pragma unroll
    for (int i = 0; i < 4; ++i)
#pragma unroll
        for (int j = 0; j < 4; ++j) acc[i][j] = (f32x4){0.f, 0.f, 0.f, 0.f};

    const int srow = tid >> 2;
    const int scol = (tid & 3) * 8;
    const int wbase = wave * 512;
    const int fr = lane & 15;
    const int fk = (lane >> 4) * 8;

    for (int k0 = 0; k0 < K; k0 += 32) {
#pragma unroll
        for (int c = 0; c < 2; ++c) {
            const unsigned short* ga = A + (size_t)(m0 + c * 64 + srow) * K + k0 + scol;
            async16(ga, As + c * 2048 + wbase);
            const unsigned short* gb = Bt + (size_t)(n0 + c * 64 + srow) * K + k0 + scol;
            async16(gb, Bs + c * 2048 + wbase);
        }
        __syncthreads();

        bf16x8 af[4], bfr[4];
#pragma unroll
        for (int mi = 0; mi < 4; ++mi)
            af[mi] = *(const bf16x8*)&As[(wm * 64 + mi * 16 + fr) * 32 + fk];
#pragma unroll
        for (int ni = 0; ni < 4; ++ni)
            bfr[ni] = *(const bf16x8*)&Bs[(wn * 64 + ni * 16 + fr) * 32 + fk];
#pragma unroll
        for (int mi = 0; mi < 4; ++mi)
#pragma unroll
            for (int ni = 0; ni < 4; ++ni)
                acc[mi][ni] = __builtin_amdgcn_mfma_f32_16x16x32_bf16(
                    af[mi], bfr[ni], acc[mi][ni], 0, 0, 0);
        __syncthreads();
    }

    const int ccol  = n0 + wn * 64 + (lane & 15);
    const int crow0 = m0 + wm * 64 + (lane >> 4) * 4;
#pragma unroll
    for (int mi = 0; mi < 4; ++mi) {
#pragma unroll
        for (int r = 0; r < 4; ++r) {
            const size_t row = (size_t)(crow0 + mi * 16 + r);
#pragma unroll
            for (int ni = 0; ni < 4; ++ni) {
                float v = acc[mi][ni][r];
                if constexpr (__is_same(OutT, float)) {
                    C[row * N + ccol + ni * 16] = v;
                } else {
                    C[row * N + ccol + ni * 16] = f2b(v);
                }
            }
        }
    }
}

// ---------------------------------------------------------------------------
// V transpose: qkv V-slice [b][t][h*64+d] -> Vt[b][h][d][t]. 64x64 LDS tiles.
// ---------------------------------------------------------------------------
__global__ __launch_bounds__(256)
void transpose_v(const unsigned short* __restrict__ qkv, unsigned short* __restrict__ vt, int T)
{
    __shared__ unsigned short tile[64 * 72];
    const int tid = threadIdx.x;
    const int k0  = blockIdx.x * 64;
    const int h   = blockIdx.y;
    const int b   = blockIdx.z;
    const size_t C3 = 3072;
    const unsigned short* vb = qkv + (size_t)b * T * C3 + 2048 + h * 64;

    const int r  = tid >> 2;
    const int c0 = (tid & 3) * 16;
    {
        const unsigned short* g = vb + (size_t)(k0 + r) * C3 + c0;
        *(float4*)&tile[r * 72 + c0]     = *(const float4*)g;
        *(float4*)&tile[r * 72 + c0 + 8] = *(const float4*)(g + 8);
    }
    __syncthreads();
    // write rows of Vt: thread d = tid>>2, t chunk (tid&3)*16
    unsigned short buf[16];
#pragma unroll
    for (int j = 0; j < 16; ++j) buf[j] = tile[(c0 + j) * 72 + r];
    unsigned short* o = vt + ((size_t)(b * 16 + h) * 64 + r) * T + k0 + c0;
    *(float4*)o       = *(float4*)&buf[0];
    *(float4*)(o + 8) = *(float4*)&buf[8];
}

// ---------------------------------------------------------------------------
// MFMA flash attention. grid (T/64, H, B), 256 thr = 4 waves; wave owns 16 q.
// LDS (bf16, row stride 72): Qs[64][72], Ks[64][72], Vts[64 d][72 kr], Ps[64][72].
// ---------------------------------------------------------------------------
__global__ __launch_bounds__(256)
void attn_mfma(const unsigned short* __restrict__ qkv,
               const unsigned short* __restrict__ vt,
               unsigned short* __restrict__ out, int T)
{
    __shared__ unsigned short Qs[64 * 72];
    __shared__ unsigned short Ks[64 * 72];
    __shared__ unsigned short Vts[64 * 72];
    __shared__ unsigned short Ps[64 * 72];

    const int tid  = threadIdx.x;
    const int lane = tid & 63;
    const int wave = tid >> 6;
    const int lc   = lane & 15;
    const int quad = lane >> 4;
    const int qt = (gridDim.x - 1) - blockIdx.x;   // heavy blocks first
    const int h  = blockIdx.y;
    const int b  = blockIdx.z;
    const int q0 = qt * 64;
    const size_t C3 = 3072;
    const unsigned short* qb  = qkv + (size_t)b * T * C3 + h * 64;
    const unsigned short* kb  = qb + 1024;
    const unsigned short* vtb = vt + (size_t)(b * 16 + h) * 64 * T;

    const int sr = tid >> 2;           // staging row 0..63
    const int sc = (tid & 3) * 16;     // staging col 0,16,32,48

    // stage Q once
    {
        const unsigned short* g = qb + (size_t)(q0 + sr) * C3 + sc;
        *(float4*)&Qs[sr * 72 + sc]     = *(const float4*)g;
        *(float4*)&Qs[sr * 72 + sc + 8] = *(const float4*)(g + 8);
    }

    f32x4 o_acc[4];
#pragma unroll
    for (int ni = 0; ni < 4; ++ni) o_acc[ni] = (f32x4){0.f, 0.f, 0.f, 0.f};
    float m_i[4], l_i[4];
#pragma unroll
    for (int r = 0; r < 4; ++r) { m_i[r] = -__builtin_inff(); l_i[r] = 0.f; }

    for (int kt = 0; kt <= qt; ++kt) {
        const int k0 = kt * 64;
        // global loads into regs
        const unsigned short* gk = kb + (size_t)(k0 + sr) * C3 + sc;
        float4 kv0 = *(const float4*)gk;
        float4 kv1 = *(const float4*)(gk + 8);
        const unsigned short* gv = vtb + (size_t)sr * T + k0 + sc;
        float4 vv0 = *(const float4*)gv;
        float4 vv1 = *(const float4*)(gv + 8);

        __syncthreads();   // prior-iter LDS reads complete
        *(float4*)&Ks[sr * 72 + sc]      = kv0;
        *(float4*)&Ks[sr * 72 + sc + 8]  = kv1;
        *(float4*)&Vts[sr * 72 + sc]     = vv0;
        *(float4*)&Vts[sr * 72 + sc + 8] = vv1;
        __syncthreads();   // staging visible (covers Qs on first iter)

        // ---- S = Q K^T  (m = wave's 16 q rows, n = 64 kr, k = d = 64)
        f32x4 s[4];
#pragma unroll
        for (int ni = 0; ni < 4; ++ni) s[ni] = (f32x4){0.f, 0.f, 0.f, 0.f};
        bf16x8 aq0 = *(const bf16x8*)&Qs[(wave * 16 + lc) * 72 + quad * 8];
        bf16x8 aq1 = *(const bf16x8*)&Qs[(wave * 16 + lc) * 72 + 32 + quad * 8];
#pragma unroll
        for (int ni = 0; ni < 4; ++ni) {
            bf16x8 bk0 = *(const bf16x8*)&Ks[(ni * 16 + lc) * 72 + quad * 8];
            bf16x8 bk1 = *(const bf16x8*)&Ks[(ni * 16 + lc) * 72 + 32 + quad * 8];
            s[ni] = __builtin_amdgcn_mfma_f32_16x16x32_bf16(aq0, bk0, s[ni], 0, 0, 0);
            s[ni] = __builtin_amdgcn_mfma_f32_16x16x32_bf16(aq1, bk1, s[ni], 0, 0, 0);
        }
        // scale + causal mask (C/D: row = quad*4+r, col = lc + ni*16)
#pragma unroll
        for (int ni = 0; ni < 4; ++ni)
#pragma unroll
            for (int r = 0; r < 4; ++r) s[ni][r] *= 0.125f;
        if (kt == qt) {
#pragma unroll
            for (int ni = 0; ni < 4; ++ni)
#pragma unroll
                for (int r = 0; r < 4; ++r)
                    if (ni * 16 + lc > wave * 16 + quad * 4 + r)
                        s[ni][r] = -__builtin_inff();
        }
        // ---- online softmax per row, write P (bf16) to LDS
#pragma unroll
        for (int r = 0; r < 4; ++r) {
            float mx = fmaxf(fmaxf(s[0][r], s[1][r]), fmaxf(s[2][r], s[3][r]));
#pragma unroll
            for (int off = 1; off < 16; off <<= 1)
                mx = fmaxf(mx, __shfl_xor(mx, off, 16));
            float m_new = fmaxf(m_i[r], mx);
            float alpha = __expf(m_i[r] - m_new);
            float p[4], rs = 0.f;
#pragma unroll
            for (int ni = 0; ni < 4; ++ni) { p[ni] = __expf(s[ni][r] - m_new); rs += p[ni]; }
#pragma unroll
            for (int off = 1; off < 16; off <<= 1)
                rs += __shfl_xor(rs, off, 16);
            l_i[r] = l_i[r] * alpha + rs;
            m_i[r] = m_new;
#pragma unroll
            for (int ni = 0; ni < 4; ++ni) o_acc[ni][r] *= alpha;
            const int prow = (wave * 16 + quad * 4 + r) * 72;
#pragma unroll
            for (int ni = 0; ni < 4; ++ni)
                Ps[prow + ni * 16 + lc] = f2b(p[ni]);
        }
        // ---- O += P V  (A-frag: own P rows; wave-internal LDS ordering suffices)
        bf16x8 ap0 = *(const bf16x8*)&Ps[(wave * 16 + lc) * 72 + quad * 8];
        bf16x8 ap1 = *(const bf16x8*)&Ps[(wave * 16 + lc) * 72 + 32 + quad * 8];
#pragma unroll
        for (int ni = 0; ni < 4; ++ni) {
            bf16x8 bv0 = *(const bf16x8*)&Vts[(ni * 16 + lc) * 72 + quad * 8];
            bf16x8 bv1 = *(const bf16x8*)&Vts[(ni * 16 + lc) * 72 + 32 + quad * 8];
            o_acc[ni] = __builtin_amdgcn_mfma_f32_16x16x32_bf16(ap0, bv0, o_acc[ni], 0, 0, 0);
            o_acc[ni] = __builtin_amdgcn_mfma_f32_16x16x32_bf16(ap1, bv1, o_acc[ni], 0, 0, 0);
        }
    }

    // epilogue: normalize, bf16, write [b][t][h*64+d]
    unsigned short* ob = out + ((size_t)b * T + q0 + wave * 16 + quad * 4) * 1024 + h * 64 + lc;
#pragma unroll
    for (int r = 0; r < 4; ++r) {
        float inv = 1.f / l_i[r];
#pragma unroll
        for (int ni = 0; ni < 4; ++ni)
            ob[(size_t)r * 1024 + ni * 16] = f2b(o_acc[ni][r] * inv);
    }
}

// ---------------------------------------------------------------------------
extern "C" void kernel_launch(void* const* d_in, const int* in_sizes, int n_in,
                              void* d_out, int out_size, void* d_ws, size_t ws_size,
                              hipStream_t stream)
{
    const float* x     = (const float*)d_in[0];
    const float* W_qkv = (const float*)d_in[1];
    const float* W_out = (const float*)d_in[2];
    float* out = (float*)d_out;

    const int C = 1024;
    const int T = 2048;
    const int M = in_sizes[0] / C;   // 8192
    const int B = M / T;             // 4
    const int n_x    = in_sizes[0];
    const int n_wqkv = in_sizes[1];
    const int n_wout = in_sizes[2];

    unsigned short* x_bf    = (unsigned short*)d_ws;
    unsigned short* wqkv_bf = x_bf    + n_x;
    unsigned short* wout_bf = wqkv_bf + n_wqkv;
    unsigned short* qkv_bf  = wout_bf + n_wout;            // M x 3C
    unsigned short* vt_bf   = qkv_bf  + (size_t)M * 3 * C; // B*H*64*T
    unsigned short* ao_bf   = vt_bf   + (size_t)B * 16 * 64 * T;

    cast_f32_bf16<<<n_x    / 2048, 256, 0, stream>>>(x,     x_bf,    n_x);
    cast_f32_bf16<<<n_wqkv / 2048, 256, 0, stream>>>(W_qkv, wqkv_bf, n_wqkv);
    cast_f32_bf16<<<n_wout / 2048, 256, 0, stream>>>(W_out, wout_bf, n_wout);

    gemm_bf16_nt<unsigned short><<<dim3((3*C)/128, M/128), 256, 0, stream>>>(
        x_bf, wqkv_bf, qkv_bf, M, 3*C, C);

    transpose_v<<<dim3(T/64, 16, B), 256, 0, stream>>>(qkv_bf, vt_bf, T);

    attn_mfma<<<dim3(T/64, 16, B), 256, 0, stream>>>(qkv_bf, vt_bf, ao_bf, T);

    gemm_bf16_nt<float><<<dim3(C/128, M/128), 256, 0, stream>>>(
        ao_bf, wout_bf, out, M, C, C);
}

// Round 4
// 416.638 us; speedup vs baseline: 4.2001x; 1.0156x over previous
//
#include <hip/hip_runtime.h>
#include <hip/hip_bf16.h>
#include <math.h>

// ---------------------------------------------------------------------------
// Round 3: attention restructure.
//   - triangle pairing: block = q-tiles (a, nq-1-a) -> uniform work, 1024 blocks
//   - Q fragments register-resident (no Q LDS), K/V staged once per pair
//   - exp2-domain online softmax (scale folded), raw v_exp_f32
//   casts / gemm_bf16_nt / transpose_v unchanged from round 2.
// ---------------------------------------------------------------------------

typedef __attribute__((ext_vector_type(8))) short bf16x8;
typedef __attribute__((ext_vector_type(4))) float f32x4;

__device__ __forceinline__ void async16(const void* g, void* l) {
    __builtin_amdgcn_global_load_lds((const __attribute__((address_space(1))) void*)g,
                                     (__attribute__((address_space(3))) void*)l,
                                     16, 0, 0);
}

__device__ __forceinline__ unsigned short f2b(float f) {
    __hip_bfloat16 h = __float2bfloat16(f);
    return *(unsigned short*)&h;
}

// ---------------------------------------------------------------------------
__global__ __launch_bounds__(256)
void cast_f32_bf16(const float* __restrict__ in, unsigned short* __restrict__ out, int n)
{
    int i = (blockIdx.x * 256 + threadIdx.x) * 8;
    if (i + 8 > n) return;
    float4 a = *(const float4*)(in + i);
    float4 b = *(const float4*)(in + i + 4);
    __hip_bfloat16 r[8];
    r[0] = __float2bfloat16(a.x); r[1] = __float2bfloat16(a.y);
    r[2] = __float2bfloat16(a.z); r[3] = __float2bfloat16(a.w);
    r[4] = __float2bfloat16(b.x); r[5] = __float2bfloat16(b.y);
    r[6] = __float2bfloat16(b.z); r[7] = __float2bfloat16(b.w);
    *(float4*)(out + i) = *(float4*)r;
}

// ---------------------------------------------------------------------------
// bf16 NT GEMM (verified): A [M,K], Bt [N,K] row-major bf16.
// ---------------------------------------------------------------------------
template <typename OutT>
__global__ __launch_bounds__(256)
void gemm_bf16_nt(const unsigned short* __restrict__ A,
                  const unsigned short* __restrict__ Bt,
                  OutT* __restrict__ C, int M, int N, int K)
{
    __shared__ unsigned short As[128 * 32];
    __shared__ unsigned short Bs[128 * 32];
    const int tid  = threadIdx.x;
    const int lane = tid & 63;
    const int wave = tid >> 6;
    const int wm   = wave >> 1;
    const int wn   = wave & 1;
    const int m0   = blockIdx.y * 128;
    const int n0   = blockIdx.x * 128;

    f32x4 acc[4][4];
#pragma unroll
    for (int i = 0; i < 4; ++i)
#pragma unroll
        for (int j = 0; j < 4; ++j) acc[i][j] = (f32x4){0.f, 0.f, 0.f, 0.f};

    const int srow = tid >> 2;
    const int scol = (tid & 3) * 8;
    const int wbase = wave * 512;
    const int fr = lane & 15;
    const int fk = (lane >> 4) * 8;

    for (int k0 = 0; k0 < K; k0 += 32) {
#pragma unroll
        for (int c = 0; c < 2; ++c) {
            const unsigned short* ga = A + (size_t)(m0 + c * 64 + srow) * K + k0 + scol;
            async16(ga, As + c * 2048 + wbase);
            const unsigned short* gb = Bt + (size_t)(n0 + c * 64 + srow) * K + k0 + scol;
            async16(gb, Bs + c * 2048 + wbase);
        }
        __syncthreads();

        bf16x8 af[4], bfr[4];
#pragma unroll
        for (int mi = 0; mi < 4; ++mi)
            af[mi] = *(const bf16x8*)&As[(wm * 64 + mi * 16 + fr) * 32 + fk];
#pragma unroll
        for (int ni = 0; ni < 4; ++ni)
            bfr[ni] = *(const bf16x8*)&Bs[(wn * 64 + ni * 16 + fr) * 32 + fk];
#pragma unroll
        for (int mi = 0; mi < 4; ++mi)
#pragma unroll
            for (int ni = 0; ni < 4; ++ni)
                acc[mi][ni] = __builtin_amdgcn_mfma_f32_16x16x32_bf16(
                    af[mi], bfr[ni], acc[mi][ni], 0, 0, 0);
        __syncthreads();
    }

    const int ccol  = n0 + wn * 64 + (lane & 15);
    const int crow0 = m0 + wm * 64 + (lane >> 4) * 4;
#pragma unroll
    for (int mi = 0; mi < 4; ++mi) {
#pragma unroll
        for (int r = 0; r < 4; ++r) {
            const size_t row = (size_t)(crow0 + mi * 16 + r);
#pragma unroll
            for (int ni = 0; ni < 4; ++ni) {
                float v = acc[mi][ni][r];
                if constexpr (__is_same(OutT, float)) {
                    C[row * N + ccol + ni * 16] = v;
                } else {
                    C[row * N + ccol + ni * 16] = f2b(v);
                }
            }
        }
    }
}

// ---------------------------------------------------------------------------
// V transpose: qkv V-slice [b][t][h*64+d] -> Vt[b][h][d][t]. 64x64 LDS tiles.
// ---------------------------------------------------------------------------
__global__ __launch_bounds__(256)
void transpose_v(const unsigned short* __restrict__ qkv, unsigned short* __restrict__ vt, int T)
{
    __shared__ unsigned short tile[64 * 72];
    const int tid = threadIdx.x;
    const int k0  = blockIdx.x * 64;
    const int h   = blockIdx.y;
    const int b   = blockIdx.z;
    const size_t C3 = 3072;
    const unsigned short* vb = qkv + (size_t)b * T * C3 + 2048 + h * 64;

    const int r  = tid >> 2;
    const int c0 = (tid & 3) * 16;
    {
        const unsigned short* g = vb + (size_t)(k0 + r) * C3 + c0;
        *(float4*)&tile[r * 72 + c0]     = *(const float4*)g;
        *(float4*)&tile[r * 72 + c0 + 8] = *(const float4*)(g + 8);
    }
    __syncthreads();
    unsigned short buf[16];
#pragma unroll
    for (int j = 0; j < 16; ++j) buf[j] = tile[(c0 + j) * 72 + r];
    unsigned short* o = vt + ((size_t)(b * 16 + h) * 64 + r) * T + k0 + c0;
    *(float4*)o       = *(float4*)&buf[0];
    *(float4*)(o + 8) = *(float4*)&buf[8];
}

// ---------------------------------------------------------------------------
// MFMA flash attention, paired q-tiles. grid (nq/2, H, B), 256 thr = 4 waves.
// Each block: q-tiles qtA=blockIdx.x (small) and qtB=nq-1-qtA (large) share
// staged K/V tiles. Q frags in registers. LDS: Ks/Vts/Ps 64x72 bf16 = 27 KB.
// ---------------------------------------------------------------------------
__global__ __launch_bounds__(256, 4)
void attn_mfma(const unsigned short* __restrict__ qkv,
               const unsigned short* __restrict__ vt,
               unsigned short* __restrict__ out, int T)
{
    __shared__ unsigned short Ks[64 * 72];
    __shared__ unsigned short Vts[64 * 72];
    __shared__ unsigned short Ps[64 * 72];

    const int tid  = threadIdx.x;
    const int lane = tid & 63;
    const int wave = tid >> 6;
    const int lc   = lane & 15;
    const int quad = lane >> 4;
    const int nq   = T >> 6;
    const int qtA  = blockIdx.x;          // 0 .. nq/2-1
    const int qtB  = nq - 1 - qtA;
    const int h    = blockIdx.y;
    const int b    = blockIdx.z;
    const size_t C3 = 3072;
    const unsigned short* qb  = qkv + (size_t)b * T * C3 + h * 64;
    const unsigned short* kb  = qb + 1024;
    const unsigned short* vtb = vt + (size_t)(b * 16 + h) * 64 * T;

    const int sr = tid >> 2;
    const int sc = (tid & 3) * 16;

    // loop-invariant Q fragments straight from global (L2-served, one-time)
    const int qrow = wave * 16 + lc;
    const unsigned short* gqA = qb + (size_t)(qtA * 64 + qrow) * C3 + quad * 8;
    bf16x8 aqA0 = *(const bf16x8*)gqA;
    bf16x8 aqA1 = *(const bf16x8*)(gqA + 32);
    const unsigned short* gqB = qb + (size_t)(qtB * 64 + qrow) * C3 + quad * 8;
    bf16x8 aqB0 = *(const bf16x8*)gqB;
    bf16x8 aqB1 = *(const bf16x8*)(gqB + 32);

    f32x4 oA[4], oB[4];
    float mA[4], lA[4], mB[4], lB[4];
#pragma unroll
    for (int i = 0; i < 4; ++i) {
        oA[i] = (f32x4){0.f, 0.f, 0.f, 0.f};
        oB[i] = (f32x4){0.f, 0.f, 0.f, 0.f};
        mA[i] = -__builtin_inff(); lA[i] = 0.f;
        mB[i] = -__builtin_inff(); lB[i] = 0.f;
    }

    const float SC = 0.18033688011112042f;   // log2(e) / sqrt(Dh)

    auto proc = [&](bf16x8 aq0, bf16x8 aq1, f32x4* o, float* m_i, float* l_i,
                    bool isdiag) {
        // ---- S = Q K^T (k = d = 64)
        f32x4 s[4];
#pragma unroll
        for (int ni = 0; ni < 4; ++ni) {
            bf16x8 bk0 = *(const bf16x8*)&Ks[(ni * 16 + lc) * 72 + quad * 8];
            bf16x8 bk1 = *(const bf16x8*)&Ks[(ni * 16 + lc) * 72 + 32 + quad * 8];
            s[ni] = (f32x4){0.f, 0.f, 0.f, 0.f};
            s[ni] = __builtin_amdgcn_mfma_f32_16x16x32_bf16(aq0, bk0, s[ni], 0, 0, 0);
            s[ni] = __builtin_amdgcn_mfma_f32_16x16x32_bf16(aq1, bk1, s[ni], 0, 0, 0);
        }
#pragma unroll
        for (int ni = 0; ni < 4; ++ni)
#pragma unroll
            for (int r = 0; r < 4; ++r) s[ni][r] *= SC;
        if (isdiag) {
#pragma unroll
            for (int ni = 0; ni < 4; ++ni)
#pragma unroll
                for (int r = 0; r < 4; ++r)
                    if (ni * 16 + lc > wave * 16 + quad * 4 + r)
                        s[ni][r] = -__builtin_inff();
        }
        // ---- online softmax (exp2 domain), write P bf16 to wave-private rows
#pragma unroll
        for (int r = 0; r < 4; ++r) {
            float mx = fmaxf(fmaxf(s[0][r], s[1][r]), fmaxf(s[2][r], s[3][r]));
#pragma unroll
            for (int off = 1; off < 16; off <<= 1)
                mx = fmaxf(mx, __shfl_xor(mx, off, 16));
            float m_new = fmaxf(m_i[r], mx);
            float alpha = __builtin_amdgcn_exp2f(m_i[r] - m_new);
            float p0 = __builtin_amdgcn_exp2f(s[0][r] - m_new);
            float p1 = __builtin_amdgcn_exp2f(s[1][r] - m_new);
            float p2 = __builtin_amdgcn_exp2f(s[2][r] - m_new);
            float p3 = __builtin_amdgcn_exp2f(s[3][r] - m_new);
            float rs = (p0 + p1) + (p2 + p3);
#pragma unroll
            for (int off = 1; off < 16; off <<= 1)
                rs += __shfl_xor(rs, off, 16);
            l_i[r] = l_i[r] * alpha + rs;
            m_i[r] = m_new;
#pragma unroll
            for (int ni = 0; ni < 4; ++ni) o[ni][r] *= alpha;
            const int prow = (wave * 16 + quad * 4 + r) * 72;
            Ps[prow + lc]      = f2b(p0);
            Ps[prow + 16 + lc] = f2b(p1);
            Ps[prow + 32 + lc] = f2b(p2);
            Ps[prow + 48 + lc] = f2b(p3);
        }
        // ---- O += P V (A-frag rows are wave-private, no barrier needed)
        bf16x8 ap0 = *(const bf16x8*)&Ps[(wave * 16 + lc) * 72 + quad * 8];
        bf16x8 ap1 = *(const bf16x8*)&Ps[(wave * 16 + lc) * 72 + 32 + quad * 8];
#pragma unroll
        for (int ni = 0; ni < 4; ++ni) {
            bf16x8 bv0 = *(const bf16x8*)&Vts[(ni * 16 + lc) * 72 + quad * 8];
            bf16x8 bv1 = *(const bf16x8*)&Vts[(ni * 16 + lc) * 72 + 32 + quad * 8];
            o[ni] = __builtin_amdgcn_mfma_f32_16x16x32_bf16(ap0, bv0, o[ni], 0, 0, 0);
            o[ni] = __builtin_amdgcn_mfma_f32_16x16x32_bf16(ap1, bv1, o[ni], 0, 0, 0);
        }
    };

    for (int kt = 0; kt <= qtB; ++kt) {
        const int k0 = kt * 64;
        const unsigned short* gk = kb + (size_t)(k0 + sr) * C3 + sc;
        float4 kv0 = *(const float4*)gk;
        float4 kv1 = *(const float4*)(gk + 8);
        const unsigned short* gv = vtb + (size_t)sr * T + k0 + sc;
        float4 vv0 = *(const float4*)gv;
        float4 vv1 = *(const float4*)(gv + 8);

        __syncthreads();   // prior-iter LDS reads complete
        *(float4*)&Ks[sr * 72 + sc]      = kv0;
        *(float4*)&Ks[sr * 72 + sc + 8]  = kv1;
        *(float4*)&Vts[sr * 72 + sc]     = vv0;
        *(float4*)&Vts[sr * 72 + sc + 8] = vv1;
        __syncthreads();   // staging visible

        proc(aqB0, aqB1, oB, mB, lB, kt == qtB);
        if (kt <= qtA)
            proc(aqA0, aqA1, oA, mA, lA, kt == qtA);
    }

    // epilogue: normalize, bf16, write [b][t][h*64+d]
    auto epi = [&](f32x4* o, float* l_i, int q0t) {
        unsigned short* ob = out + ((size_t)b * T + q0t + wave * 16 + quad * 4) * 1024 + h * 64 + lc;
#pragma unroll
        for (int r = 0; r < 4; ++r) {
            float inv = 1.f / l_i[r];
#pragma unroll
            for (int ni = 0; ni < 4; ++ni)
                ob[(size_t)r * 1024 + ni * 16] = f2b(o[ni][r] * inv);
        }
    };
    epi(oB, lB, qtB * 64);
    epi(oA, lA, qtA * 64);
}

// ---------------------------------------------------------------------------
extern "C" void kernel_launch(void* const* d_in, const int* in_sizes, int n_in,
                              void* d_out, int out_size, void* d_ws, size_t ws_size,
                              hipStream_t stream)
{
    const float* x     = (const float*)d_in[0];
    const float* W_qkv = (const float*)d_in[1];
    const float* W_out = (const float*)d_in[2];
    float* out = (float*)d_out;

    const int C = 1024;
    const int T = 2048;
    const int M = in_sizes[0] / C;   // 8192
    const int B = M / T;             // 4
    const int n_x    = in_sizes[0];
    const int n_wqkv = in_sizes[1];
    const int n_wout = in_sizes[2];

    unsigned short* x_bf    = (unsigned short*)d_ws;
    unsigned short* wqkv_bf = x_bf    + n_x;
    unsigned short* wout_bf = wqkv_bf + n_wqkv;
    unsigned short* qkv_bf  = wout_bf + n_wout;            // M x 3C
    unsigned short* vt_bf   = qkv_bf  + (size_t)M * 3 * C; // B*H*64*T
    unsigned short* ao_bf   = vt_bf   + (size_t)B * 16 * 64 * T;

    cast_f32_bf16<<<n_x    / 2048, 256, 0, stream>>>(x,     x_bf,    n_x);
    cast_f32_bf16<<<n_wqkv / 2048, 256, 0, stream>>>(W_qkv, wqkv_bf, n_wqkv);
    cast_f32_bf16<<<n_wout / 2048, 256, 0, stream>>>(W_out, wout_bf, n_wout);

    gemm_bf16_nt<unsigned short><<<dim3((3*C)/128, M/128), 256, 0, stream>>>(
        x_bf, wqkv_bf, qkv_bf, M, 3*C, C);

    transpose_v<<<dim3(T/64, 16, B), 256, 0, stream>>>(qkv_bf, vt_bf, T);

    attn_mfma<<<dim3((T/64)/2, 16, B), 256, 0, stream>>>(qkv_bf, vt_bf, ao_bf, T);

    gemm_bf16_nt<float><<<dim3(C/128, M/128), 256, 0, stream>>>(
        ao_bf, wout_bf, out, M, C, C);
}

// Round 5
// 321.777 us; speedup vs baseline: 5.4383x; 1.2948x over previous
//
#include <hip/hip_runtime.h>
#include <hip/hip_bf16.h>
#include <math.h>

// ---------------------------------------------------------------------------
// Round 4: fix round-3 scratch spill (pointer-arg lambda blocked mem2reg ->
//   429 MB scratch writes). State now in constant-indexed arrays under an
//   unrolled tile loop. XCD swizzle: all 16 pair-blocks of a (b,h) share
//   bid%8 -> same XCD L2 -> K/V tiles L2-resident (8 bh x 512 KB = 4 MB).
//   casts / gemm_bf16_nt / transpose_v unchanged (verified).
// ---------------------------------------------------------------------------

typedef __attribute__((ext_vector_type(8))) short bf16x8;
typedef __attribute__((ext_vector_type(4))) float f32x4;

__device__ __forceinline__ void async16(const void* g, void* l) {
    __builtin_amdgcn_global_load_lds((const __attribute__((address_space(1))) void*)g,
                                     (__attribute__((address_space(3))) void*)l,
                                     16, 0, 0);
}

__device__ __forceinline__ unsigned short f2b(float f) {
    __hip_bfloat16 h = __float2bfloat16(f);
    return *(unsigned short*)&h;
}

// ---------------------------------------------------------------------------
__global__ __launch_bounds__(256)
void cast_f32_bf16(const float* __restrict__ in, unsigned short* __restrict__ out, int n)
{
    int i = (blockIdx.x * 256 + threadIdx.x) * 8;
    if (i + 8 > n) return;
    float4 a = *(const float4*)(in + i);
    float4 b = *(const float4*)(in + i + 4);
    __hip_bfloat16 r[8];
    r[0] = __float2bfloat16(a.x); r[1] = __float2bfloat16(a.y);
    r[2] = __float2bfloat16(a.z); r[3] = __float2bfloat16(a.w);
    r[4] = __float2bfloat16(b.x); r[5] = __float2bfloat16(b.y);
    r[6] = __float2bfloat16(b.z); r[7] = __float2bfloat16(b.w);
    *(float4*)(out + i) = *(float4*)r;
}

// ---------------------------------------------------------------------------
// bf16 NT GEMM (verified): A [M,K], Bt [N,K] row-major bf16.
// ---------------------------------------------------------------------------
template <typename OutT>
__global__ __launch_bounds__(256)
void gemm_bf16_nt(const unsigned short* __restrict__ A,
                  const unsigned short* __restrict__ Bt,
                  OutT* __restrict__ C, int M, int N, int K)
{
    __shared__ unsigned short As[128 * 32];
    __shared__ unsigned short Bs[128 * 32];
    const int tid  = threadIdx.x;
    const int lane = tid & 63;
    const int wave = tid >> 6;
    const int wm   = wave >> 1;
    const int wn   = wave & 1;
    const int m0   = blockIdx.y * 128;
    const int n0   = blockIdx.x * 128;

    f32x4 acc[4][4];
#pragma unroll
    for (int i = 0; i < 4; ++i)
#pragma unroll
        for (int j = 0; j < 4; ++j) acc[i][j] = (f32x4){0.f, 0.f, 0.f, 0.f};

    const int srow = tid >> 2;
    const int scol = (tid & 3) * 8;
    const int wbase = wave * 512;
    const int fr = lane & 15;
    const int fk = (lane >> 4) * 8;

    for (int k0 = 0; k0 < K; k0 += 32) {
#pragma unroll
        for (int c = 0; c < 2; ++c) {
            const unsigned short* ga = A + (size_t)(m0 + c * 64 + srow) * K + k0 + scol;
            async16(ga, As + c * 2048 + wbase);
            const unsigned short* gb = Bt + (size_t)(n0 + c * 64 + srow) * K + k0 + scol;
            async16(gb, Bs + c * 2048 + wbase);
        }
        __syncthreads();

        bf16x8 af[4], bfr[4];
#pragma unroll
        for (int mi = 0; mi < 4; ++mi)
            af[mi] = *(const bf16x8*)&As[(wm * 64 + mi * 16 + fr) * 32 + fk];
#pragma unroll
        for (int ni = 0; ni < 4; ++ni)
            bfr[ni] = *(const bf16x8*)&Bs[(wn * 64 + ni * 16 + fr) * 32 + fk];
#pragma unroll
        for (int mi = 0; mi < 4; ++mi)
#pragma unroll
            for (int ni = 0; ni < 4; ++ni)
                acc[mi][ni] = __builtin_amdgcn_mfma_f32_16x16x32_bf16(
                    af[mi], bfr[ni], acc[mi][ni], 0, 0, 0);
        __syncthreads();
    }

    const int ccol  = n0 + wn * 64 + (lane & 15);
    const int crow0 = m0 + wm * 64 + (lane >> 4) * 4;
#pragma unroll
    for (int mi = 0; mi < 4; ++mi) {
#pragma unroll
        for (int r = 0; r < 4; ++r) {
            const size_t row = (size_t)(crow0 + mi * 16 + r);
#pragma unroll
            for (int ni = 0; ni < 4; ++ni) {
                float v = acc[mi][ni][r];
                if constexpr (__is_same(OutT, float)) {
                    C[row * N + ccol + ni * 16] = v;
                } else {
                    C[row * N + ccol + ni * 16] = f2b(v);
                }
            }
        }
    }
}

// ---------------------------------------------------------------------------
// V transpose: qkv V-slice [b][t][h*64+d] -> Vt[b][h][d][t]. 64x64 LDS tiles.
// ---------------------------------------------------------------------------
__global__ __launch_bounds__(256)
void transpose_v(const unsigned short* __restrict__ qkv, unsigned short* __restrict__ vt, int T)
{
    __shared__ unsigned short tile[64 * 72];
    const int tid = threadIdx.x;
    const int k0  = blockIdx.x * 64;
    const int h   = blockIdx.y;
    const int b   = blockIdx.z;
    const size_t C3 = 3072;
    const unsigned short* vb = qkv + (size_t)b * T * C3 + 2048 + h * 64;

    const int r  = tid >> 2;
    const int c0 = (tid & 3) * 16;
    {
        const unsigned short* g = vb + (size_t)(k0 + r) * C3 + c0;
        *(float4*)&tile[r * 72 + c0]     = *(const float4*)g;
        *(float4*)&tile[r * 72 + c0 + 8] = *(const float4*)(g + 8);
    }
    __syncthreads();
    unsigned short buf[16];
#pragma unroll
    for (int j = 0; j < 16; ++j) buf[j] = tile[(c0 + j) * 72 + r];
    unsigned short* o = vt + ((size_t)(b * 16 + h) * 64 + r) * T + k0 + c0;
    *(float4*)o       = *(float4*)&buf[0];
    *(float4*)(o + 8) = *(float4*)&buf[8];
}

// ---------------------------------------------------------------------------
// MFMA flash attention, paired q-tiles, 1D grid of B*H*(nq/2) = 1024 blocks.
// bid decode: bh = bid & 63 (so bid%8 == bh%8 -> same XCD per bh), a = bid>>6.
// Tile t=0: qt = nq-1-a (long), t=1: qt = a (short). 4 waves, wave owns 16 q.
// All per-tile state in constant-indexed arrays (register-resident).
// LDS: Ks/Vts/Ps 64x72 bf16 = 27 KB.
// ---------------------------------------------------------------------------
__global__ __launch_bounds__(256, 4)
void attn_mfma(const unsigned short* __restrict__ qkv,
               const unsigned short* __restrict__ vt,
               unsigned short* __restrict__ out, int T)
{
    __shared__ unsigned short Ks[64 * 72];
    __shared__ unsigned short Vts[64 * 72];
    __shared__ unsigned short Ps[64 * 72];

    const int tid  = threadIdx.x;
    const int lane = tid & 63;
    const int wave = tid >> 6;
    const int lc   = lane & 15;
    const int quad = lane >> 4;
    const int nq   = T >> 6;
    const int bid  = blockIdx.x;
    const int bh   = bid & 63;
    const int a    = bid >> 6;
    const int b    = bh >> 4;
    const int h    = bh & 15;
    int qt[2];
    qt[0] = nq - 1 - a;    // long tile
    qt[1] = a;             // short tile
    const size_t C3 = 3072;
    const unsigned short* qb  = qkv + (size_t)b * T * C3 + h * 64;
    const unsigned short* kb  = qb + 1024;
    const unsigned short* vtb = vt + (size_t)(b * 16 + h) * 64 * T;

    const int sr = tid >> 2;
    const int sc = (tid & 3) * 16;

    // loop-invariant Q fragments from global (one-time)
    const int qrow = wave * 16 + lc;
    bf16x8 qf[2][2];
#pragma unroll
    for (int t = 0; t < 2; ++t) {
        const unsigned short* gq = qb + (size_t)(qt[t] * 64 + qrow) * C3 + quad * 8;
        qf[t][0] = *(const bf16x8*)gq;
        qf[t][1] = *(const bf16x8*)(gq + 32);
    }

    f32x4 o_[2][4];
    float m_[2][4], l_[2][4];
#pragma unroll
    for (int t = 0; t < 2; ++t)
#pragma unroll
        for (int i = 0; i < 4; ++i) {
            o_[t][i] = (f32x4){0.f, 0.f, 0.f, 0.f};
            m_[t][i] = -__builtin_inff();
            l_[t][i] = 0.f;
        }

    const float SC = 0.18033688011112042f;   // log2(e) / sqrt(Dh)

    for (int kt = 0; kt <= qt[0]; ++kt) {
        const int k0 = kt * 64;
        const unsigned short* gk = kb + (size_t)(k0 + sr) * C3 + sc;
        float4 kv0 = *(const float4*)gk;
        float4 kv1 = *(const float4*)(gk + 8);
        const unsigned short* gv = vtb + (size_t)sr * T + k0 + sc;
        float4 vv0 = *(const float4*)gv;
        float4 vv1 = *(const float4*)(gv + 8);

        __syncthreads();   // prior-iter LDS reads complete
        *(float4*)&Ks[sr * 72 + sc]      = kv0;
        *(float4*)&Ks[sr * 72 + sc + 8]  = kv1;
        *(float4*)&Vts[sr * 72 + sc]     = vv0;
        *(float4*)&Vts[sr * 72 + sc + 8] = vv1;
        __syncthreads();   // staging visible

#pragma unroll
        for (int t = 0; t < 2; ++t) {
            if (t == 1 && kt > qt[1]) break;   // short tile done
            const bool isdiag = (kt == qt[t]);

            // ---- S = Q K^T (k = d = 64)
            f32x4 s[4];
#pragma unroll
            for (int ni = 0; ni < 4; ++ni) {
                bf16x8 bk0 = *(const bf16x8*)&Ks[(ni * 16 + lc) * 72 + quad * 8];
                bf16x8 bk1 = *(const bf16x8*)&Ks[(ni * 16 + lc) * 72 + 32 + quad * 8];
                s[ni] = (f32x4){0.f, 0.f, 0.f, 0.f};
                s[ni] = __builtin_amdgcn_mfma_f32_16x16x32_bf16(qf[t][0], bk0, s[ni], 0, 0, 0);
                s[ni] = __builtin_amdgcn_mfma_f32_16x16x32_bf16(qf[t][1], bk1, s[ni], 0, 0, 0);
            }
            if (isdiag) {
#pragma unroll
                for (int ni = 0; ni < 4; ++ni)
#pragma unroll
                    for (int r = 0; r < 4; ++r)
                        if (ni * 16 + lc > wave * 16 + quad * 4 + r)
                            s[ni][r] = -__builtin_inff();
            }
            // ---- online softmax (exp2 domain, scale folded into fmaf)
#pragma unroll
            for (int r = 0; r < 4; ++r) {
                float mx = fmaxf(fmaxf(s[0][r], s[1][r]), fmaxf(s[2][r], s[3][r]));
#pragma unroll
                for (int off = 1; off < 16; off <<= 1)
                    mx = fmaxf(mx, __shfl_xor(mx, off, 16));
                float m_new = fmaxf(m_[t][r], mx);
                float msc   = m_new * SC;
                float alpha = __builtin_amdgcn_exp2f(fmaf(m_[t][r], SC, -msc));
                float p0 = __builtin_amdgcn_exp2f(fmaf(s[0][r], SC, -msc));
                float p1 = __builtin_amdgcn_exp2f(fmaf(s[1][r], SC, -msc));
                float p2 = __builtin_amdgcn_exp2f(fmaf(s[2][r], SC, -msc));
                float p3 = __builtin_amdgcn_exp2f(fmaf(s[3][r], SC, -msc));
                float rs = (p0 + p1) + (p2 + p3);
#pragma unroll
                for (int off = 1; off < 16; off <<= 1)
                    rs += __shfl_xor(rs, off, 16);
                l_[t][r] = l_[t][r] * alpha + rs;
                m_[t][r] = m_new;
#pragma unroll
                for (int ni = 0; ni < 4; ++ni) o_[t][ni][r] *= alpha;
                const int prow = (wave * 16 + quad * 4 + r) * 72;
                Ps[prow + lc]      = f2b(p0);
                Ps[prow + 16 + lc] = f2b(p1);
                Ps[prow + 32 + lc] = f2b(p2);
                Ps[prow + 48 + lc] = f2b(p3);
            }
            // ---- O += P V (P rows wave-private; no barrier needed)
            bf16x8 ap0 = *(const bf16x8*)&Ps[(wave * 16 + lc) * 72 + quad * 8];
            bf16x8 ap1 = *(const bf16x8*)&Ps[(wave * 16 + lc) * 72 + 32 + quad * 8];
#pragma unroll
            for (int ni = 0; ni < 4; ++ni) {
                bf16x8 bv0 = *(const bf16x8*)&Vts[(ni * 16 + lc) * 72 + quad * 8];
                bf16x8 bv1 = *(const bf16x8*)&Vts[(ni * 16 + lc) * 72 + 32 + quad * 8];
                o_[t][ni] = __builtin_amdgcn_mfma_f32_16x16x32_bf16(ap0, bv0, o_[t][ni], 0, 0, 0);
                o_[t][ni] = __builtin_amdgcn_mfma_f32_16x16x32_bf16(ap1, bv1, o_[t][ni], 0, 0, 0);
            }
        }
    }

    // epilogue: normalize, bf16, write [b][t][h*64+d]
#pragma unroll
    for (int t = 0; t < 2; ++t) {
        unsigned short* ob = out + ((size_t)b * T + qt[t] * 64 + wave * 16 + quad * 4) * 1024
                           + h * 64 + lc;
#pragma unroll
        for (int r = 0; r < 4; ++r) {
            float inv = 1.f / l_[t][r];
#pragma unroll
            for (int ni = 0; ni < 4; ++ni)
                ob[(size_t)r * 1024 + ni * 16] = f2b(o_[t][ni][r] * inv);
        }
    }
}

// ---------------------------------------------------------------------------
extern "C" void kernel_launch(void* const* d_in, const int* in_sizes, int n_in,
                              void* d_out, int out_size, void* d_ws, size_t ws_size,
                              hipStream_t stream)
{
    const float* x     = (const float*)d_in[0];
    const float* W_qkv = (const float*)d_in[1];
    const float* W_out = (const float*)d_in[2];
    float* out = (float*)d_out;

    const int C = 1024;
    const int T = 2048;
    const int M = in_sizes[0] / C;   // 8192
    const int B = M / T;             // 4
    const int n_x    = in_sizes[0];
    const int n_wqkv = in_sizes[1];
    const int n_wout = in_sizes[2];

    unsigned short* x_bf    = (unsigned short*)d_ws;
    unsigned short* wqkv_bf = x_bf    + n_x;
    unsigned short* wout_bf = wqkv_bf + n_wqkv;
    unsigned short* qkv_bf  = wout_bf + n_wout;            // M x 3C
    unsigned short* vt_bf   = qkv_bf  + (size_t)M * 3 * C; // B*H*64*T
    unsigned short* ao_bf   = vt_bf   + (size_t)B * 16 * 64 * T;

    cast_f32_bf16<<<n_x    / 2048, 256, 0, stream>>>(x,     x_bf,    n_x);
    cast_f32_bf16<<<n_wqkv / 2048, 256, 0, stream>>>(W_qkv, wqkv_bf, n_wqkv);
    cast_f32_bf16<<<n_wout / 2048, 256, 0, stream>>>(W_out, wout_bf, n_wout);

    gemm_bf16_nt<unsigned short><<<dim3((3*C)/128, M/128), 256, 0, stream>>>(
        x_bf, wqkv_bf, qkv_bf, M, 3*C, C);

    transpose_v<<<dim3(T/64, 16, B), 256, 0, stream>>>(qkv_bf, vt_bf, T);

    const int nq = T / 64;
    attn_mfma<<<dim3(B * 16 * (nq / 2)), 256, 0, stream>>>(qkv_bf, vt_bf, ao_bf, T);

    gemm_bf16_nt<float><<<dim3(C/128, M/128), 256, 0, stream>>>(
        ao_bf, wout_bf, out, M, C, C);
}

// Round 6
// 272.929 us; speedup vs baseline: 6.4116x; 1.1790x over previous
//
#include <hip/hip_runtime.h>
#include <hip/hip_bf16.h>
#include <math.h>

// ---------------------------------------------------------------------------
// Round 5: static-max softmax in attention.
//   - p = exp2(s_scaled - 8): exact softmax (common factor cancels); kills
//     online-max machinery (max tree, alpha, O-rescale, m-state) and defers
//     the l cross-lane reduction to the epilogue (pure sum now).
//   - score scale log2(e)/sqrt(Dh) folded into GEMM1 epilogue (q cols only).
//   casts / transpose_v unchanged. gemm_bf16_nt gains (sc_ncols, sc) epilogue
//   scaling args.
// ---------------------------------------------------------------------------

typedef __attribute__((ext_vector_type(8))) short bf16x8;
typedef __attribute__((ext_vector_type(4))) float f32x4;

__device__ __forceinline__ void async16(const void* g, void* l) {
    __builtin_amdgcn_global_load_lds((const __attribute__((address_space(1))) void*)g,
                                     (__attribute__((address_space(3))) void*)l,
                                     16, 0, 0);
}

__device__ __forceinline__ unsigned short f2b(float f) {
    __hip_bfloat16 h = __float2bfloat16(f);
    return *(unsigned short*)&h;
}

// ---------------------------------------------------------------------------
__global__ __launch_bounds__(256)
void cast_f32_bf16(const float* __restrict__ in, unsigned short* __restrict__ out, int n)
{
    int i = (blockIdx.x * 256 + threadIdx.x) * 8;
    if (i + 8 > n) return;
    float4 a = *(const float4*)(in + i);
    float4 b = *(const float4*)(in + i + 4);
    __hip_bfloat16 r[8];
    r[0] = __float2bfloat16(a.x); r[1] = __float2bfloat16(a.y);
    r[2] = __float2bfloat16(a.z); r[3] = __float2bfloat16(a.w);
    r[4] = __float2bfloat16(b.x); r[5] = __float2bfloat16(b.y);
    r[6] = __float2bfloat16(b.z); r[7] = __float2bfloat16(b.w);
    *(float4*)(out + i) = *(float4*)r;
}

// ---------------------------------------------------------------------------
// bf16 NT GEMM (verified): A [M,K], Bt [N,K] row-major bf16.
// Epilogue multiplies columns [0, sc_ncols) by sc (used to fold the attention
// score scale into the q-slice of the QKV projection).
// ---------------------------------------------------------------------------
template <typename OutT>
__global__ __launch_bounds__(256)
void gemm_bf16_nt(const unsigned short* __restrict__ A,
                  const unsigned short* __restrict__ Bt,
                  OutT* __restrict__ C, int M, int N, int K,
                  int sc_ncols, float sc)
{
    __shared__ unsigned short As[128 * 32];
    __shared__ unsigned short Bs[128 * 32];
    const int tid  = threadIdx.x;
    const int lane = tid & 63;
    const int wave = tid >> 6;
    const int wm   = wave >> 1;
    const int wn   = wave & 1;
    const int m0   = blockIdx.y * 128;
    const int n0   = blockIdx.x * 128;

    f32x4 acc[4][4];
#pragma unroll
    for (int i = 0; i < 4; ++i)
#pragma unroll
        for (int j = 0; j < 4; ++j) acc[i][j] = (f32x4){0.f, 0.f, 0.f, 0.f};

    const int srow = tid >> 2;
    const int scol = (tid & 3) * 8;
    const int wbase = wave * 512;
    const int fr = lane & 15;
    const int fk = (lane >> 4) * 8;

    for (int k0 = 0; k0 < K; k0 += 32) {
#pragma unroll
        for (int c = 0; c < 2; ++c) {
            const unsigned short* ga = A + (size_t)(m0 + c * 64 + srow) * K + k0 + scol;
            async16(ga, As + c * 2048 + wbase);
            const unsigned short* gb = Bt + (size_t)(n0 + c * 64 + srow) * K + k0 + scol;
            async16(gb, Bs + c * 2048 + wbase);
        }
        __syncthreads();

        bf16x8 af[4], bfr[4];
#pragma unroll
        for (int mi = 0; mi < 4; ++mi)
            af[mi] = *(const bf16x8*)&As[(wm * 64 + mi * 16 + fr) * 32 + fk];
#pragma unroll
        for (int ni = 0; ni < 4; ++ni)
            bfr[ni] = *(const bf16x8*)&Bs[(wn * 64 + ni * 16 + fr) * 32 + fk];
#pragma unroll
        for (int mi = 0; mi < 4; ++mi)
#pragma unroll
            for (int ni = 0; ni < 4; ++ni)
                acc[mi][ni] = __builtin_amdgcn_mfma_f32_16x16x32_bf16(
                    af[mi], bfr[ni], acc[mi][ni], 0, 0, 0);
        __syncthreads();
    }

    const int ccol  = n0 + wn * 64 + (lane & 15);
    const int crow0 = m0 + wm * 64 + (lane >> 4) * 4;
#pragma unroll
    for (int mi = 0; mi < 4; ++mi) {
#pragma unroll
        for (int r = 0; r < 4; ++r) {
            const size_t row = (size_t)(crow0 + mi * 16 + r);
#pragma unroll
            for (int ni = 0; ni < 4; ++ni) {
                float mult = (ccol + ni * 16 < sc_ncols) ? sc : 1.0f;
                float v = acc[mi][ni][r] * mult;
                if constexpr (__is_same(OutT, float)) {
                    C[row * N + ccol + ni * 16] = v;
                } else {
                    C[row * N + ccol + ni * 16] = f2b(v);
                }
            }
        }
    }
}

// ---------------------------------------------------------------------------
// V transpose: qkv V-slice [b][t][h*64+d] -> Vt[b][h][d][t]. 64x64 LDS tiles.
// ---------------------------------------------------------------------------
__global__ __launch_bounds__(256)
void transpose_v(const unsigned short* __restrict__ qkv, unsigned short* __restrict__ vt, int T)
{
    __shared__ unsigned short tile[64 * 72];
    const int tid = threadIdx.x;
    const int k0  = blockIdx.x * 64;
    const int h   = blockIdx.y;
    const int b   = blockIdx.z;
    const size_t C3 = 3072;
    const unsigned short* vb = qkv + (size_t)b * T * C3 + 2048 + h * 64;

    const int r  = tid >> 2;
    const int c0 = (tid & 3) * 16;
    {
        const unsigned short* g = vb + (size_t)(k0 + r) * C3 + c0;
        *(float4*)&tile[r * 72 + c0]     = *(const float4*)g;
        *(float4*)&tile[r * 72 + c0 + 8] = *(const float4*)(g + 8);
    }
    __syncthreads();
    unsigned short buf[16];
#pragma unroll
    for (int j = 0; j < 16; ++j) buf[j] = tile[(c0 + j) * 72 + r];
    unsigned short* o = vt + ((size_t)(b * 16 + h) * 64 + r) * T + k0 + c0;
    *(float4*)o       = *(float4*)&buf[0];
    *(float4*)(o + 8) = *(float4*)&buf[8];
}

// ---------------------------------------------------------------------------
// MFMA flash attention, paired q-tiles, static-max softmax.
// grid: 1D B*H*(nq/2) = 1024 blocks; bh = bid & 63 (XCD-local per bh), a = bid>>6.
// Tile t=0: qt = nq-1-a (long), t=1: qt = a (short). 4 waves, wave owns 16 q.
// Q arrives pre-scaled by log2(e)/sqrt(Dh) (GEMM1 epilogue), so
//   p = exp2(s - 8) is exact softmax up to a common 2^-8 factor that cancels.
// l is a plain sum -> per-lane partials, one cross-lane reduce in epilogue.
// LDS: Ks/Vts/Ps 64x72 bf16 = 27 KB.
// ---------------------------------------------------------------------------
__global__ __launch_bounds__(256, 4)
void attn_mfma(const unsigned short* __restrict__ qkv,
               const unsigned short* __restrict__ vt,
               unsigned short* __restrict__ out, int T)
{
    __shared__ unsigned short Ks[64 * 72];
    __shared__ unsigned short Vts[64 * 72];
    __shared__ unsigned short Ps[64 * 72];

    const int tid  = threadIdx.x;
    const int lane = tid & 63;
    const int wave = tid >> 6;
    const int lc   = lane & 15;
    const int quad = lane >> 4;
    const int nq   = T >> 6;
    const int bid  = blockIdx.x;
    const int bh   = bid & 63;
    const int a    = bid >> 6;
    const int b    = bh >> 4;
    const int h    = bh & 15;
    int qt[2];
    qt[0] = nq - 1 - a;    // long tile
    qt[1] = a;             // short tile
    const size_t C3 = 3072;
    const unsigned short* qb  = qkv + (size_t)b * T * C3 + h * 64;
    const unsigned short* kb  = qb + 1024;
    const unsigned short* vtb = vt + (size_t)(b * 16 + h) * 64 * T;

    const int sr = tid >> 2;
    const int sc = (tid & 3) * 16;

    // loop-invariant Q fragments from global (one-time; Q pre-scaled)
    const int qrow = wave * 16 + lc;
    bf16x8 qf[2][2];
#pragma unroll
    for (int t = 0; t < 2; ++t) {
        const unsigned short* gq = qb + (size_t)(qt[t] * 64 + qrow) * C3 + quad * 8;
        qf[t][0] = *(const bf16x8*)gq;
        qf[t][1] = *(const bf16x8*)(gq + 32);
    }

    f32x4 o_[2][4];
    float l_[2][4];
#pragma unroll
    for (int t = 0; t < 2; ++t)
#pragma unroll
        for (int i = 0; i < 4; ++i) {
            o_[t][i] = (f32x4){0.f, 0.f, 0.f, 0.f};
            l_[t][i] = 0.f;
        }

    const float MB = 8.0f;    // static max bound in exp2 domain (~17 sigma)

    for (int kt = 0; kt <= qt[0]; ++kt) {
        const int k0 = kt * 64;
        const unsigned short* gk = kb + (size_t)(k0 + sr) * C3 + sc;
        float4 kv0 = *(const float4*)gk;
        float4 kv1 = *(const float4*)(gk + 8);
        const unsigned short* gv = vtb + (size_t)sr * T + k0 + sc;
        float4 vv0 = *(const float4*)gv;
        float4 vv1 = *(const float4*)(gv + 8);

        __syncthreads();   // prior-iter LDS reads complete
        *(float4*)&Ks[sr * 72 + sc]      = kv0;
        *(float4*)&Ks[sr * 72 + sc + 8]  = kv1;
        *(float4*)&Vts[sr * 72 + sc]     = vv0;
        *(float4*)&Vts[sr * 72 + sc + 8] = vv1;
        __syncthreads();   // staging visible

#pragma unroll
        for (int t = 0; t < 2; ++t) {
            if (t == 1 && kt > qt[1]) break;   // short tile done
            const bool isdiag = (kt == qt[t]);

            // ---- S = Q K^T (k = d = 64), s already in exp2 domain
            f32x4 s[4];
#pragma unroll
            for (int ni = 0; ni < 4; ++ni) {
                bf16x8 bk0 = *(const bf16x8*)&Ks[(ni * 16 + lc) * 72 + quad * 8];
                bf16x8 bk1 = *(const bf16x8*)&Ks[(ni * 16 + lc) * 72 + 32 + quad * 8];
                s[ni] = (f32x4){0.f, 0.f, 0.f, 0.f};
                s[ni] = __builtin_amdgcn_mfma_f32_16x16x32_bf16(qf[t][0], bk0, s[ni], 0, 0, 0);
                s[ni] = __builtin_amdgcn_mfma_f32_16x16x32_bf16(qf[t][1], bk1, s[ni], 0, 0, 0);
            }
            if (isdiag) {
#pragma unroll
                for (int ni = 0; ni < 4; ++ni)
#pragma unroll
                    for (int r = 0; r < 4; ++r)
                        if (ni * 16 + lc > wave * 16 + quad * 4 + r)
                            s[ni][r] = -__builtin_inff();
            }
            // ---- p = exp2(s - MB); accumulate per-lane l partials; P -> LDS
#pragma unroll
            for (int r = 0; r < 4; ++r) {
                float p0 = __builtin_amdgcn_exp2f(s[0][r] - MB);
                float p1 = __builtin_amdgcn_exp2f(s[1][r] - MB);
                float p2 = __builtin_amdgcn_exp2f(s[2][r] - MB);
                float p3 = __builtin_amdgcn_exp2f(s[3][r] - MB);
                l_[t][r] += (p0 + p1) + (p2 + p3);
                const int prow = (wave * 16 + quad * 4 + r) * 72;
                Ps[prow + lc]      = f2b(p0);
                Ps[prow + 16 + lc] = f2b(p1);
                Ps[prow + 32 + lc] = f2b(p2);
                Ps[prow + 48 + lc] = f2b(p3);
            }
            // ---- O += P V (P rows wave-private; no barrier needed)
            bf16x8 ap0 = *(const bf16x8*)&Ps[(wave * 16 + lc) * 72 + quad * 8];
            bf16x8 ap1 = *(const bf16x8*)&Ps[(wave * 16 + lc) * 72 + 32 + quad * 8];
#pragma unroll
            for (int ni = 0; ni < 4; ++ni) {
                bf16x8 bv0 = *(const bf16x8*)&Vts[(ni * 16 + lc) * 72 + quad * 8];
                bf16x8 bv1 = *(const bf16x8*)&Vts[(ni * 16 + lc) * 72 + 32 + quad * 8];
                o_[t][ni] = __builtin_amdgcn_mfma_f32_16x16x32_bf16(ap0, bv0, o_[t][ni], 0, 0, 0);
                o_[t][ni] = __builtin_amdgcn_mfma_f32_16x16x32_bf16(ap1, bv1, o_[t][ni], 0, 0, 0);
            }
        }
    }

    // epilogue: one cross-lane l reduction per row, normalize, write bf16
#pragma unroll
    for (int t = 0; t < 2; ++t) {
        unsigned short* ob = out + ((size_t)b * T + qt[t] * 64 + wave * 16 + quad * 4) * 1024
                           + h * 64 + lc;
#pragma unroll
        for (int r = 0; r < 4; ++r) {
            float rs = l_[t][r];
#pragma unroll
            for (int off = 1; off < 16; off <<= 1)
                rs += __shfl_xor(rs, off, 16);
            float inv = 1.f / rs;
#pragma unroll
            for (int ni = 0; ni < 4; ++ni)
                ob[(size_t)r * 1024 + ni * 16] = f2b(o_[t][ni][r] * inv);
        }
    }
}

// ---------------------------------------------------------------------------
extern "C" void kernel_launch(void* const* d_in, const int* in_sizes, int n_in,
                              void* d_out, int out_size, void* d_ws, size_t ws_size,
                              hipStream_t stream)
{
    const float* x     = (const float*)d_in[0];
    const float* W_qkv = (const float*)d_in[1];
    const float* W_out = (const float*)d_in[2];
    float* out = (float*)d_out;

    const int C = 1024;
    const int T = 2048;
    const int M = in_sizes[0] / C;   // 8192
    const int B = M / T;             // 4
    const int n_x    = in_sizes[0];
    const int n_wqkv = in_sizes[1];
    const int n_wout = in_sizes[2];

    unsigned short* x_bf    = (unsigned short*)d_ws;
    unsigned short* wqkv_bf = x_bf    + n_x;
    unsigned short* wout_bf = wqkv_bf + n_wqkv;
    unsigned short* qkv_bf  = wout_bf + n_wout;            // M x 3C
    unsigned short* vt_bf   = qkv_bf  + (size_t)M * 3 * C; // B*H*64*T
    unsigned short* ao_bf   = vt_bf   + (size_t)B * 16 * 64 * T;

    cast_f32_bf16<<<n_x    / 2048, 256, 0, stream>>>(x,     x_bf,    n_x);
    cast_f32_bf16<<<n_wqkv / 2048, 256, 0, stream>>>(W_qkv, wqkv_bf, n_wqkv);
    cast_f32_bf16<<<n_wout / 2048, 256, 0, stream>>>(W_out, wout_bf, n_wout);

    // q columns pre-scaled by log2(e)/sqrt(Dh) for exp2-domain softmax
    const float QSC = 0.18033688011112042f;
    gemm_bf16_nt<unsigned short><<<dim3((3*C)/128, M/128), 256, 0, stream>>>(
        x_bf, wqkv_bf, qkv_bf, M, 3*C, C, C, QSC);

    transpose_v<<<dim3(T/64, 16, B), 256, 0, stream>>>(qkv_bf, vt_bf, T);

    const int nq = T / 64;
    attn_mfma<<<dim3(B * 16 * (nq / 2)), 256, 0, stream>>>(qkv_bf, vt_bf, ao_bf, T);

    gemm_bf16_nt<float><<<dim3(C/128, M/128), 256, 0, stream>>>(
        ao_bf, wout_bf, out, M, C, C, 0, 1.0f);
}

// Round 7
// 263.922 us; speedup vs baseline: 6.6305x; 1.0341x over previous
//
#include <hip/hip_runtime.h>
#include <hip/hip_bf16.h>
#include <math.h>

// ---------------------------------------------------------------------------
// Round 6: attention S-transpose restructure (LDS-BW was the bottleneck).
//   - S^T = K*Q^T via MFMA operand swap (frag register layouts identical).
//     Lane then owns one q-column (lc) and k-contiguous runs -> P writes are
//     4x ds_write_b64 (was 16x ds_write_b16), l is a per-lane scalar summed
//     once in the epilogue, O^T epilogue packs 4 consecutive d (b64 stores).
//   - K/V A-frags hoisted: read once per kt, shared by both paired q-tiles
//     (phased S0,S1 -> V frags -> PV0,PV1 keeps VGPR peak < 128).
//   casts / gemm_bf16_nt / transpose_v unchanged (verified).
// ---------------------------------------------------------------------------

typedef __attribute__((ext_vector_type(8))) short bf16x8;
typedef __attribute__((ext_vector_type(4))) float f32x4;

__device__ __forceinline__ void async16(const void* g, void* l) {
    __builtin_amdgcn_global_load_lds((const __attribute__((address_space(1))) void*)g,
                                     (__attribute__((address_space(3))) void*)l,
                                     16, 0, 0);
}

__device__ __forceinline__ unsigned short f2b(float f) {
    __hip_bfloat16 h = __float2bfloat16(f);
    return *(unsigned short*)&h;
}

__device__ __forceinline__ unsigned int packbf2(float a, float b) {
    __hip_bfloat162 h2 = __float22bfloat162_rn(make_float2(a, b));
    return *(unsigned int*)&h2;
}

// ---------------------------------------------------------------------------
__global__ __launch_bounds__(256)
void cast_f32_bf16(const float* __restrict__ in, unsigned short* __restrict__ out, int n)
{
    int i = (blockIdx.x * 256 + threadIdx.x) * 8;
    if (i + 8 > n) return;
    float4 a = *(const float4*)(in + i);
    float4 b = *(const float4*)(in + i + 4);
    __hip_bfloat16 r[8];
    r[0] = __float2bfloat16(a.x); r[1] = __float2bfloat16(a.y);
    r[2] = __float2bfloat16(a.z); r[3] = __float2bfloat16(a.w);
    r[4] = __float2bfloat16(b.x); r[5] = __float2bfloat16(b.y);
    r[6] = __float2bfloat16(b.z); r[7] = __float2bfloat16(b.w);
    *(float4*)(out + i) = *(float4*)r;
}

// ---------------------------------------------------------------------------
// bf16 NT GEMM (verified): A [M,K], Bt [N,K] row-major bf16.
// Epilogue multiplies columns [0, sc_ncols) by sc.
// ---------------------------------------------------------------------------
template <typename OutT>
__global__ __launch_bounds__(256)
void gemm_bf16_nt(const unsigned short* __restrict__ A,
                  const unsigned short* __restrict__ Bt,
                  OutT* __restrict__ C, int M, int N, int K,
                  int sc_ncols, float sc)
{
    __shared__ unsigned short As[128 * 32];
    __shared__ unsigned short Bs[128 * 32];
    const int tid  = threadIdx.x;
    const int lane = tid & 63;
    const int wave = tid >> 6;
    const int wm   = wave >> 1;
    const int wn   = wave & 1;
    const int m0   = blockIdx.y * 128;
    const int n0   = blockIdx.x * 128;

    f32x4 acc[4][4];
#pragma unroll
    for (int i = 0; i < 4; ++i)
#pragma unroll
        for (int j = 0; j < 4; ++j) acc[i][j] = (f32x4){0.f, 0.f, 0.f, 0.f};

    const int srow = tid >> 2;
    const int scol = (tid & 3) * 8;
    const int wbase = wave * 512;
    const int fr = lane & 15;
    const int fk = (lane >> 4) * 8;

    for (int k0 = 0; k0 < K; k0 += 32) {
#pragma unroll
        for (int c = 0; c < 2; ++c) {
            const unsigned short* ga = A + (size_t)(m0 + c * 64 + srow) * K + k0 + scol;
            async16(ga, As + c * 2048 + wbase);
            const unsigned short* gb = Bt + (size_t)(n0 + c * 64 + srow) * K + k0 + scol;
            async16(gb, Bs + c * 2048 + wbase);
        }
        __syncthreads();

        bf16x8 af[4], bfr[4];
#pragma unroll
        for (int mi = 0; mi < 4; ++mi)
            af[mi] = *(const bf16x8*)&As[(wm * 64 + mi * 16 + fr) * 32 + fk];
#pragma unroll
        for (int ni = 0; ni < 4; ++ni)
            bfr[ni] = *(const bf16x8*)&Bs[(wn * 64 + ni * 16 + fr) * 32 + fk];
#pragma unroll
        for (int mi = 0; mi < 4; ++mi)
#pragma unroll
            for (int ni = 0; ni < 4; ++ni)
                acc[mi][ni] = __builtin_amdgcn_mfma_f32_16x16x32_bf16(
                    af[mi], bfr[ni], acc[mi][ni], 0, 0, 0);
        __syncthreads();
    }

    const int ccol  = n0 + wn * 64 + (lane & 15);
    const int crow0 = m0 + wm * 64 + (lane >> 4) * 4;
#pragma unroll
    for (int mi = 0; mi < 4; ++mi) {
#pragma unroll
        for (int r = 0; r < 4; ++r) {
            const size_t row = (size_t)(crow0 + mi * 16 + r);
#pragma unroll
            for (int ni = 0; ni < 4; ++ni) {
                float mult = (ccol + ni * 16 < sc_ncols) ? sc : 1.0f;
                float v = acc[mi][ni][r] * mult;
                if constexpr (__is_same(OutT, float)) {
                    C[row * N + ccol + ni * 16] = v;
                } else {
                    C[row * N + ccol + ni * 16] = f2b(v);
                }
            }
        }
    }
}

// ---------------------------------------------------------------------------
// V transpose: qkv V-slice [b][t][h*64+d] -> Vt[b][h][d][t]. 64x64 LDS tiles.
// ---------------------------------------------------------------------------
__global__ __launch_bounds__(256)
void transpose_v(const unsigned short* __restrict__ qkv, unsigned short* __restrict__ vt, int T)
{
    __shared__ unsigned short tile[64 * 72];
    const int tid = threadIdx.x;
    const int k0  = blockIdx.x * 64;
    const int h   = blockIdx.y;
    const int b   = blockIdx.z;
    const size_t C3 = 3072;
    const unsigned short* vb = qkv + (size_t)b * T * C3 + 2048 + h * 64;

    const int r  = tid >> 2;
    const int c0 = (tid & 3) * 16;
    {
        const unsigned short* g = vb + (size_t)(k0 + r) * C3 + c0;
        *(float4*)&tile[r * 72 + c0]     = *(const float4*)g;
        *(float4*)&tile[r * 72 + c0 + 8] = *(const float4*)(g + 8);
    }
    __syncthreads();
    unsigned short buf[16];
#pragma unroll
    for (int j = 0; j < 16; ++j) buf[j] = tile[(c0 + j) * 72 + r];
    unsigned short* o = vt + ((size_t)(b * 16 + h) * 64 + r) * T + k0 + c0;
    *(float4*)o       = *(float4*)&buf[0];
    *(float4*)(o + 8) = *(float4*)&buf[8];
}

// ---------------------------------------------------------------------------
// MFMA flash attention, paired q-tiles, S^T formulation, static-max softmax.
// grid: 1D B*H*(nq/2) = 1024 blocks; bh = bid & 63 (XCD-local), a = bid >> 6.
// t=0: qt=nq-1-a (long), t=1: qt=a (short). 4 waves; wave owns 16 q (lc = q).
// Per kt: stage K,V -> K A-frags (shared) -> S^T_t = K*Q_t^T -> p=exp2(s-MB)
//   -> Ps[t] b64 writes -> V A-frags (shared) -> O_t^T += V^T * P_t^T.
// LDS: Ks, Vts, Ps[2] @ 64x72 bf16 = 36 KB -> 4 blocks/CU.
// ---------------------------------------------------------------------------
__global__ __launch_bounds__(256, 4)
void attn_mfma(const unsigned short* __restrict__ qkv,
               const unsigned short* __restrict__ vt,
               unsigned short* __restrict__ out, int T)
{
    __shared__ unsigned short Ks[64 * 72];
    __shared__ unsigned short Vts[64 * 72];
    __shared__ unsigned short Ps[2][64 * 72];

    const int tid  = threadIdx.x;
    const int lane = tid & 63;
    const int wave = tid >> 6;
    const int lc   = lane & 15;
    const int quad = lane >> 4;
    const int nq   = T >> 6;
    const int bid  = blockIdx.x;
    const int bh   = bid & 63;
    const int a    = bid >> 6;
    const int b    = bh >> 4;
    const int h    = bh & 15;
    int qt[2];
    qt[0] = nq - 1 - a;    // long tile
    qt[1] = a;             // short tile
    const size_t C3 = 3072;
    const unsigned short* qb  = qkv + (size_t)b * T * C3 + h * 64;
    const unsigned short* kb  = qb + 1024;
    const unsigned short* vtb = vt + (size_t)(b * 16 + h) * 64 * T;

    const int sr = tid >> 2;
    const int sc = (tid & 3) * 16;

    // loop-invariant Q fragments (pre-scaled by log2(e)/sqrt(Dh) in GEMM1).
    // As B-operand: lane holds Q[q = wave*16+lc][d = quad*8 + j] — same
    // register content as the old A-operand layout.
    const int qrow = wave * 16 + lc;
    bf16x8 qf[2][2];
#pragma unroll
    for (int t = 0; t < 2; ++t) {
        const unsigned short* gq = qb + (size_t)(qt[t] * 64 + qrow) * C3 + quad * 8;
        qf[t][0] = *(const bf16x8*)gq;
        qf[t][1] = *(const bf16x8*)(gq + 32);
    }

    // O^T accumulators: o_[t][mi][r] = O^T[d = mi*16+quad*4+r][q = lc]
    f32x4 o_[2][4];
    float l_[2];
#pragma unroll
    for (int t = 0; t < 2; ++t) {
        l_[t] = 0.f;
#pragma unroll
        for (int i = 0; i < 4; ++i) o_[t][i] = (f32x4){0.f, 0.f, 0.f, 0.f};
    }

    const float MB = 8.0f;   // static exp2-domain max bound (~17 sigma)

    for (int kt = 0; kt <= qt[0]; ++kt) {
        const int k0 = kt * 64;
        const unsigned short* gk = kb + (size_t)(k0 + sr) * C3 + sc;
        float4 kv0 = *(const float4*)gk;
        float4 kv1 = *(const float4*)(gk + 8);
        const unsigned short* gv = vtb + (size_t)sr * T + k0 + sc;
        float4 vv0 = *(const float4*)gv;
        float4 vv1 = *(const float4*)(gv + 8);

        __syncthreads();   // prior-iter LDS reads complete
        *(float4*)&Ks[sr * 72 + sc]      = kv0;
        *(float4*)&Ks[sr * 72 + sc + 8]  = kv1;
        *(float4*)&Vts[sr * 72 + sc]     = vv0;
        *(float4*)&Vts[sr * 72 + sc + 8] = vv1;
        __syncthreads();   // staging visible

        // ---- K A-frags: A[m = kr = mi*16+lc][d], shared by both tiles
        bf16x8 ak[4][2];
#pragma unroll
        for (int mi = 0; mi < 4; ++mi) {
            ak[mi][0] = *(const bf16x8*)&Ks[(mi * 16 + lc) * 72 + quad * 8];
            ak[mi][1] = *(const bf16x8*)&Ks[(mi * 16 + lc) * 72 + 32 + quad * 8];
        }

        // ---- S^T phase (both tiles): D[m=kr][n=q] = sum_d K[kr][d] Q[q][d]
#pragma unroll
        for (int t = 0; t < 2; ++t) {
            if (t == 1 && kt > qt[1]) break;
            f32x4 s[4];
#pragma unroll
            for (int mi = 0; mi < 4; ++mi) {
                s[mi] = (f32x4){0.f, 0.f, 0.f, 0.f};
                s[mi] = __builtin_amdgcn_mfma_f32_16x16x32_bf16(ak[mi][0], qf[t][0], s[mi], 0, 0, 0);
                s[mi] = __builtin_amdgcn_mfma_f32_16x16x32_bf16(ak[mi][1], qf[t][1], s[mi], 0, 0, 0);
            }
            // causal mask: kr_global > q_global
            if (kt == qt[t]) {
                const int qg = qt[t] * 64 + wave * 16 + lc;
                const int kbase = k0 + quad * 4;
#pragma unroll
                for (int mi = 0; mi < 4; ++mi)
#pragma unroll
                    for (int r = 0; r < 4; ++r)
                        if (kbase + mi * 16 + r > qg)
                            s[mi][r] = -__builtin_inff();
            }
            // p = exp2(s - MB); per-lane l partial; P^T rows -> b64 writes
            float lacc = 0.f;
            const int prow = (wave * 16 + lc) * 72 + quad * 4;
#pragma unroll
            for (int mi = 0; mi < 4; ++mi) {
                float p0 = __builtin_amdgcn_exp2f(s[mi][0] - MB);
                float p1 = __builtin_amdgcn_exp2f(s[mi][1] - MB);
                float p2 = __builtin_amdgcn_exp2f(s[mi][2] - MB);
                float p3 = __builtin_amdgcn_exp2f(s[mi][3] - MB);
                lacc += (p0 + p1) + (p2 + p3);
                uint2 pk;
                pk.x = packbf2(p0, p1);
                pk.y = packbf2(p2, p3);
                *(uint2*)&Ps[t][prow + mi * 16] = pk;
            }
            l_[t] += lacc;
        }

        // ---- V A-frags: A[m = d = mi*16+lc][kr], shared by both tiles
        bf16x8 av[4][2];
#pragma unroll
        for (int mi = 0; mi < 4; ++mi) {
            av[mi][0] = *(const bf16x8*)&Vts[(mi * 16 + lc) * 72 + quad * 8];
            av[mi][1] = *(const bf16x8*)&Vts[(mi * 16 + lc) * 72 + 32 + quad * 8];
        }

        // ---- PV phase: O^T[d][q] += sum_kr V^T[d][kr] P^T[kr][q]
#pragma unroll
        for (int t = 0; t < 2; ++t) {
            if (t == 1 && kt > qt[1]) break;
            bf16x8 bp0 = *(const bf16x8*)&Ps[t][(wave * 16 + lc) * 72 + quad * 8];
            bf16x8 bp1 = *(const bf16x8*)&Ps[t][(wave * 16 + lc) * 72 + 32 + quad * 8];
#pragma unroll
            for (int mi = 0; mi < 4; ++mi) {
                o_[t][mi] = __builtin_amdgcn_mfma_f32_16x16x32_bf16(av[mi][0], bp0, o_[t][mi], 0, 0, 0);
                o_[t][mi] = __builtin_amdgcn_mfma_f32_16x16x32_bf16(av[mi][1], bp1, o_[t][mi], 0, 0, 0);
            }
        }
    }

    // epilogue: l total (quads partition k: xor 16, 32), normalize, b64 stores
#pragma unroll
    for (int t = 0; t < 2; ++t) {
        float rs = l_[t];
        rs += __shfl_xor(rs, 16);
        rs += __shfl_xor(rs, 32);
        float inv = 1.f / rs;
        unsigned short* ob = out + ((size_t)b * T + qt[t] * 64 + wave * 16 + lc) * 1024
                           + h * 64 + quad * 4;
#pragma unroll
        for (int mi = 0; mi < 4; ++mi) {
            uint2 pk;
            pk.x = packbf2(o_[t][mi][0] * inv, o_[t][mi][1] * inv);
            pk.y = packbf2(o_[t][mi][2] * inv, o_[t][mi][3] * inv);
            *(uint2*)(ob + mi * 16) = pk;
        }
    }
}

// ---------------------------------------------------------------------------
extern "C" void kernel_launch(void* const* d_in, const int* in_sizes, int n_in,
                              void* d_out, int out_size, void* d_ws, size_t ws_size,
                              hipStream_t stream)
{
    const float* x     = (const float*)d_in[0];
    const float* W_qkv = (const float*)d_in[1];
    const float* W_out = (const float*)d_in[2];
    float* out = (float*)d_out;

    const int C = 1024;
    const int T = 2048;
    const int M = in_sizes[0] / C;   // 8192
    const int B = M / T;             // 4
    const int n_x    = in_sizes[0];
    const int n_wqkv = in_sizes[1];
    const int n_wout = in_sizes[2];

    unsigned short* x_bf    = (unsigned short*)d_ws;
    unsigned short* wqkv_bf = x_bf    + n_x;
    unsigned short* wout_bf = wqkv_bf + n_wqkv;
    unsigned short* qkv_bf  = wout_bf + n_wout;            // M x 3C
    unsigned short* vt_bf   = qkv_bf  + (size_t)M * 3 * C; // B*H*64*T
    unsigned short* ao_bf   = vt_bf   + (size_t)B * 16 * 64 * T;

    cast_f32_bf16<<<n_x    / 2048, 256, 0, stream>>>(x,     x_bf,    n_x);
    cast_f32_bf16<<<n_wqkv / 2048, 256, 0, stream>>>(W_qkv, wqkv_bf, n_wqkv);
    cast_f32_bf16<<<n_wout / 2048, 256, 0, stream>>>(W_out, wout_bf, n_wout);

    // q columns pre-scaled by log2(e)/sqrt(Dh) for exp2-domain softmax
    const float QSC = 0.18033688011112042f;
    gemm_bf16_nt<unsigned short><<<dim3((3*C)/128, M/128), 256, 0, stream>>>(
        x_bf, wqkv_bf, qkv_bf, M, 3*C, C, C, QSC);

    transpose_v<<<dim3(T/64, 16, B), 256, 0, stream>>>(qkv_bf, vt_bf, T);

    const int nq = T / 64;
    attn_mfma<<<dim3(B * 16 * (nq / 2)), 256, 0, stream>>>(qkv_bf, vt_bf, ao_bf, T);

    gemm_bf16_nt<float><<<dim3(C/128, M/128), 256, 0, stream>>>(
        ao_bf, wout_bf, out, M, C, C, 0, 1.0f);
}

// Round 8
// 251.759 us; speedup vs baseline: 6.9508x; 1.0483x over previous
//
#include <hip/hip_runtime.h>
#include <hip/hip_bf16.h>
#include <math.h>

// ---------------------------------------------------------------------------
// Round 7: BK=64 GEMM (two 32-k sub-tiles per barrier pair -> half the
//   barrier/drain overhead; each sub-tile keeps the verified 64B-row LDS
//   layout so ds_read bank behavior is unchanged). Fused single cast kernel.
//   attn_mfma / transpose_v unchanged (verified round 6).
// ---------------------------------------------------------------------------

typedef __attribute__((ext_vector_type(8))) short bf16x8;
typedef __attribute__((ext_vector_type(4))) float f32x4;

__device__ __forceinline__ void async16(const void* g, void* l) {
    __builtin_amdgcn_global_load_lds((const __attribute__((address_space(1))) void*)g,
                                     (__attribute__((address_space(3))) void*)l,
                                     16, 0, 0);
}

__device__ __forceinline__ unsigned short f2b(float f) {
    __hip_bfloat16 h = __float2bfloat16(f);
    return *(unsigned short*)&h;
}

__device__ __forceinline__ unsigned int packbf2(float a, float b) {
    __hip_bfloat162 h2 = __float22bfloat162_rn(make_float2(a, b));
    return *(unsigned int*)&h2;
}

// ---------------------------------------------------------------------------
// Fused cast: three fp32 arrays -> bf16 in one launch. Sizes divisible by 2048.
// ---------------------------------------------------------------------------
__global__ __launch_bounds__(256)
void cast3_f32_bf16(const float* __restrict__ a, unsigned short* __restrict__ oa, int na,
                    const float* __restrict__ b, unsigned short* __restrict__ ob, int nb,
                    const float* __restrict__ c, unsigned short* __restrict__ oc, int nc)
{
    const int bid  = blockIdx.x;
    const int na_b = na >> 11;
    const int nb_b = nb >> 11;
    const float* in;
    unsigned short* out;
    int base;
    if (bid < na_b)             { in = a; out = oa; base = bid; }
    else if (bid < na_b + nb_b) { in = b; out = ob; base = bid - na_b; }
    else                        { in = c; out = oc; base = bid - na_b - nb_b; }
    int i = (base * 256 + threadIdx.x) * 8;
    float4 x = *(const float4*)(in + i);
    float4 y = *(const float4*)(in + i + 4);
    __hip_bfloat16 r[8];
    r[0] = __float2bfloat16(x.x); r[1] = __float2bfloat16(x.y);
    r[2] = __float2bfloat16(x.z); r[3] = __float2bfloat16(x.w);
    r[4] = __float2bfloat16(y.x); r[5] = __float2bfloat16(y.y);
    r[6] = __float2bfloat16(y.z); r[7] = __float2bfloat16(y.w);
    *(float4*)(out + i) = *(float4*)r;
}

// ---------------------------------------------------------------------------
// bf16 NT GEMM, BK=64: A [M,K], Bt [N,K] row-major bf16.
// LDS [2][128x32] per matrix (32 KB total); 32 MFMAs per barrier pair.
// Epilogue multiplies columns [0, sc_ncols) by sc.
// ---------------------------------------------------------------------------
template <typename OutT>
__global__ __launch_bounds__(256)
void gemm_bf16_nt(const unsigned short* __restrict__ A,
                  const unsigned short* __restrict__ Bt,
                  OutT* __restrict__ C, int M, int N, int K,
                  int sc_ncols, float sc)
{
    __shared__ unsigned short As[2 * 128 * 32];
    __shared__ unsigned short Bs[2 * 128 * 32];
    const int tid  = threadIdx.x;
    const int lane = tid & 63;
    const int wave = tid >> 6;
    const int wm   = wave >> 1;
    const int wn   = wave & 1;
    const int m0   = blockIdx.y * 128;
    const int n0   = blockIdx.x * 128;

    f32x4 acc[4][4];
#pragma unroll
    for (int i = 0; i < 4; ++i)
#pragma unroll
        for (int j = 0; j < 4; ++j) acc[i][j] = (f32x4){0.f, 0.f, 0.f, 0.f};

    const int srow = tid >> 2;          // 0..63 (64B rows, 4 lanes/row)
    const int scol = (tid & 3) * 8;     // 0,8,16,24 elems
    const int wbase = wave * 512;       // 1 KB per wave chunk (ushorts)
    const int fr = lane & 15;
    const int fk = (lane >> 4) * 8;

    for (int k0 = 0; k0 < K; k0 += 64) {
#pragma unroll
        for (int ks = 0; ks < 2; ++ks) {
#pragma unroll
            for (int c = 0; c < 2; ++c) {
                const unsigned short* ga =
                    A + (size_t)(m0 + c * 64 + srow) * K + k0 + ks * 32 + scol;
                async16(ga, As + ks * 4096 + c * 2048 + wbase);
                const unsigned short* gb =
                    Bt + (size_t)(n0 + c * 64 + srow) * K + k0 + ks * 32 + scol;
                async16(gb, Bs + ks * 4096 + c * 2048 + wbase);
            }
        }
        __syncthreads();   // drain vmcnt + all waves arrived

#pragma unroll
        for (int ks = 0; ks < 2; ++ks) {
            bf16x8 af[4], bfr[4];
#pragma unroll
            for (int mi = 0; mi < 4; ++mi)
                af[mi] = *(const bf16x8*)&As[ks * 4096 + (wm * 64 + mi * 16 + fr) * 32 + fk];
#pragma unroll
            for (int ni = 0; ni < 4; ++ni)
                bfr[ni] = *(const bf16x8*)&Bs[ks * 4096 + (wn * 64 + ni * 16 + fr) * 32 + fk];
#pragma unroll
            for (int mi = 0; mi < 4; ++mi)
#pragma unroll
                for (int ni = 0; ni < 4; ++ni)
                    acc[mi][ni] = __builtin_amdgcn_mfma_f32_16x16x32_bf16(
                        af[mi], bfr[ni], acc[mi][ni], 0, 0, 0);
        }
        __syncthreads();   // all waves done reading before next stage
    }

    const int ccol  = n0 + wn * 64 + (lane & 15);
    const int crow0 = m0 + wm * 64 + (lane >> 4) * 4;
#pragma unroll
    for (int mi = 0; mi < 4; ++mi) {
#pragma unroll
        for (int r = 0; r < 4; ++r) {
            const size_t row = (size_t)(crow0 + mi * 16 + r);
#pragma unroll
            for (int ni = 0; ni < 4; ++ni) {
                float mult = (ccol + ni * 16 < sc_ncols) ? sc : 1.0f;
                float v = acc[mi][ni][r] * mult;
                if constexpr (__is_same(OutT, float)) {
                    C[row * N + ccol + ni * 16] = v;
                } else {
                    C[row * N + ccol + ni * 16] = f2b(v);
                }
            }
        }
    }
}

// ---------------------------------------------------------------------------
// V transpose: qkv V-slice [b][t][h*64+d] -> Vt[b][h][d][t]. 64x64 LDS tiles.
// ---------------------------------------------------------------------------
__global__ __launch_bounds__(256)
void transpose_v(const unsigned short* __restrict__ qkv, unsigned short* __restrict__ vt, int T)
{
    __shared__ unsigned short tile[64 * 72];
    const int tid = threadIdx.x;
    const int k0  = blockIdx.x * 64;
    const int h   = blockIdx.y;
    const int b   = blockIdx.z;
    const size_t C3 = 3072;
    const unsigned short* vb = qkv + (size_t)b * T * C3 + 2048 + h * 64;

    const int r  = tid >> 2;
    const int c0 = (tid & 3) * 16;
    {
        const unsigned short* g = vb + (size_t)(k0 + r) * C3 + c0;
        *(float4*)&tile[r * 72 + c0]     = *(const float4*)g;
        *(float4*)&tile[r * 72 + c0 + 8] = *(const float4*)(g + 8);
    }
    __syncthreads();
    unsigned short buf[16];
#pragma unroll
    for (int j = 0; j < 16; ++j) buf[j] = tile[(c0 + j) * 72 + r];
    unsigned short* o = vt + ((size_t)(b * 16 + h) * 64 + r) * T + k0 + c0;
    *(float4*)o       = *(float4*)&buf[0];
    *(float4*)(o + 8) = *(float4*)&buf[8];
}

// ---------------------------------------------------------------------------
// MFMA flash attention, paired q-tiles, S^T formulation, static-max softmax.
// (unchanged from round 6 — verified)
// ---------------------------------------------------------------------------
__global__ __launch_bounds__(256, 4)
void attn_mfma(const unsigned short* __restrict__ qkv,
               const unsigned short* __restrict__ vt,
               unsigned short* __restrict__ out, int T)
{
    __shared__ unsigned short Ks[64 * 72];
    __shared__ unsigned short Vts[64 * 72];
    __shared__ unsigned short Ps[2][64 * 72];

    const int tid  = threadIdx.x;
    const int lane = tid & 63;
    const int wave = tid >> 6;
    const int lc   = lane & 15;
    const int quad = lane >> 4;
    const int nq   = T >> 6;
    const int bid  = blockIdx.x;
    const int bh   = bid & 63;
    const int a    = bid >> 6;
    const int b    = bh >> 4;
    const int h    = bh & 15;
    int qt[2];
    qt[0] = nq - 1 - a;    // long tile
    qt[1] = a;             // short tile
    const size_t C3 = 3072;
    const unsigned short* qb  = qkv + (size_t)b * T * C3 + h * 64;
    const unsigned short* kb  = qb + 1024;
    const unsigned short* vtb = vt + (size_t)(b * 16 + h) * 64 * T;

    const int sr = tid >> 2;
    const int sc = (tid & 3) * 16;

    const int qrow = wave * 16 + lc;
    bf16x8 qf[2][2];
#pragma unroll
    for (int t = 0; t < 2; ++t) {
        const unsigned short* gq = qb + (size_t)(qt[t] * 64 + qrow) * C3 + quad * 8;
        qf[t][0] = *(const bf16x8*)gq;
        qf[t][1] = *(const bf16x8*)(gq + 32);
    }

    f32x4 o_[2][4];
    float l_[2];
#pragma unroll
    for (int t = 0; t < 2; ++t) {
        l_[t] = 0.f;
#pragma unroll
        for (int i = 0; i < 4; ++i) o_[t][i] = (f32x4){0.f, 0.f, 0.f, 0.f};
    }

    const float MB = 8.0f;   // static exp2-domain max bound (~17 sigma)

    for (int kt = 0; kt <= qt[0]; ++kt) {
        const int k0 = kt * 64;
        const unsigned short* gk = kb + (size_t)(k0 + sr) * C3 + sc;
        float4 kv0 = *(const float4*)gk;
        float4 kv1 = *(const float4*)(gk + 8);
        const unsigned short* gv = vtb + (size_t)sr * T + k0 + sc;
        float4 vv0 = *(const float4*)gv;
        float4 vv1 = *(const float4*)(gv + 8);

        __syncthreads();
        *(float4*)&Ks[sr * 72 + sc]      = kv0;
        *(float4*)&Ks[sr * 72 + sc + 8]  = kv1;
        *(float4*)&Vts[sr * 72 + sc]     = vv0;
        *(float4*)&Vts[sr * 72 + sc + 8] = vv1;
        __syncthreads();

        bf16x8 ak[4][2];
#pragma unroll
        for (int mi = 0; mi < 4; ++mi) {
            ak[mi][0] = *(const bf16x8*)&Ks[(mi * 16 + lc) * 72 + quad * 8];
            ak[mi][1] = *(const bf16x8*)&Ks[(mi * 16 + lc) * 72 + 32 + quad * 8];
        }

#pragma unroll
        for (int t = 0; t < 2; ++t) {
            if (t == 1 && kt > qt[1]) break;
            f32x4 s[4];
#pragma unroll
            for (int mi = 0; mi < 4; ++mi) {
                s[mi] = (f32x4){0.f, 0.f, 0.f, 0.f};
                s[mi] = __builtin_amdgcn_mfma_f32_16x16x32_bf16(ak[mi][0], qf[t][0], s[mi], 0, 0, 0);
                s[mi] = __builtin_amdgcn_mfma_f32_16x16x32_bf16(ak[mi][1], qf[t][1], s[mi], 0, 0, 0);
            }
            if (kt == qt[t]) {
                const int qg = qt[t] * 64 + wave * 16 + lc;
                const int kbase = k0 + quad * 4;
#pragma unroll
                for (int mi = 0; mi < 4; ++mi)
#pragma unroll
                    for (int r = 0; r < 4; ++r)
                        if (kbase + mi * 16 + r > qg)
                            s[mi][r] = -__builtin_inff();
            }
            float lacc = 0.f;
            const int prow = (wave * 16 + lc) * 72 + quad * 4;
#pragma unroll
            for (int mi = 0; mi < 4; ++mi) {
                float p0 = __builtin_amdgcn_exp2f(s[mi][0] - MB);
                float p1 = __builtin_amdgcn_exp2f(s[mi][1] - MB);
                float p2 = __builtin_amdgcn_exp2f(s[mi][2] - MB);
                float p3 = __builtin_amdgcn_exp2f(s[mi][3] - MB);
                lacc += (p0 + p1) + (p2 + p3);
                uint2 pk;
                pk.x = packbf2(p0, p1);
                pk.y = packbf2(p2, p3);
                *(uint2*)&Ps[t][prow + mi * 16] = pk;
            }
            l_[t] += lacc;
        }

        bf16x8 av[4][2];
#pragma unroll
        for (int mi = 0; mi < 4; ++mi) {
            av[mi][0] = *(const bf16x8*)&Vts[(mi * 16 + lc) * 72 + quad * 8];
            av[mi][1] = *(const bf16x8*)&Vts[(mi * 16 + lc) * 72 + 32 + quad * 8];
        }

#pragma unroll
        for (int t = 0; t < 2; ++t) {
            if (t == 1 && kt > qt[1]) break;
            bf16x8 bp0 = *(const bf16x8*)&Ps[t][(wave * 16 + lc) * 72 + quad * 8];
            bf16x8 bp1 = *(const bf16x8*)&Ps[t][(wave * 16 + lc) * 72 + 32 + quad * 8];
#pragma unroll
            for (int mi = 0; mi < 4; ++mi) {
                o_[t][mi] = __builtin_amdgcn_mfma_f32_16x16x32_bf16(av[mi][0], bp0, o_[t][mi], 0, 0, 0);
                o_[t][mi] = __builtin_amdgcn_mfma_f32_16x16x32_bf16(av[mi][1], bp1, o_[t][mi], 0, 0, 0);
            }
        }
    }

#pragma unroll
    for (int t = 0; t < 2; ++t) {
        float rs = l_[t];
        rs += __shfl_xor(rs, 16);
        rs += __shfl_xor(rs, 32);
        float inv = 1.f / rs;
        unsigned short* ob = out + ((size_t)b * T + qt[t] * 64 + wave * 16 + lc) * 1024
                           + h * 64 + quad * 4;
#pragma unroll
        for (int mi = 0; mi < 4; ++mi) {
            uint2 pk;
            pk.x = packbf2(o_[t][mi][0] * inv, o_[t][mi][1] * inv);
            pk.y = packbf2(o_[t][mi][2] * inv, o_[t][mi][3] * inv);
            *(uint2*)(ob + mi * 16) = pk;
        }
    }
}

// ---------------------------------------------------------------------------
extern "C" void kernel_launch(void* const* d_in, const int* in_sizes, int n_in,
                              void* d_out, int out_size, void* d_ws, size_t ws_size,
                              hipStream_t stream)
{
    const float* x     = (const float*)d_in[0];
    const float* W_qkv = (const float*)d_in[1];
    const float* W_out = (const float*)d_in[2];
    float* out = (float*)d_out;

    const int C = 1024;
    const int T = 2048;
    const int M = in_sizes[0] / C;   // 8192
    const int B = M / T;             // 4
    const int n_x    = in_sizes[0];
    const int n_wqkv = in_sizes[1];
    const int n_wout = in_sizes[2];

    unsigned short* x_bf    = (unsigned short*)d_ws;
    unsigned short* wqkv_bf = x_bf    + n_x;
    unsigned short* wout_bf = wqkv_bf + n_wqkv;
    unsigned short* qkv_bf  = wout_bf + n_wout;            // M x 3C
    unsigned short* vt_bf   = qkv_bf  + (size_t)M * 3 * C; // B*H*64*T
    unsigned short* ao_bf   = vt_bf   + (size_t)B * 16 * 64 * T;

    cast3_f32_bf16<<<(n_x + n_wqkv + n_wout) / 2048, 256, 0, stream>>>(
        x, x_bf, n_x, W_qkv, wqkv_bf, n_wqkv, W_out, wout_bf, n_wout);

    // q columns pre-scaled by log2(e)/sqrt(Dh) for exp2-domain softmax
    const float QSC = 0.18033688011112042f;
    gemm_bf16_nt<unsigned short><<<dim3((3*C)/128, M/128), 256, 0, stream>>>(
        x_bf, wqkv_bf, qkv_bf, M, 3*C, C, C, QSC);

    transpose_v<<<dim3(T/64, 16, B), 256, 0, stream>>>(qkv_bf, vt_bf, T);

    const int nq = T / 64;
    attn_mfma<<<dim3(B * 16 * (nq / 2)), 256, 0, stream>>>(qkv_bf, vt_bf, ao_bf, T);

    gemm_bf16_nt<float><<<dim3(C/128, M/128), 256, 0, stream>>>(
        ao_bf, wout_bf, out, M, C, C, 0, 1.0f);
}